// Round 8
// baseline (360.771 us; speedup 1.0000x reference)
//
#include <hip/hip_runtime.h>
#include <math.h>

#define NN 50000
#define NE 800000
#define FD 128      // IN == HC == 128
#define NB 64
#define NBUK 196            // ceil(NN/256) buckets of 256 dst nodes
#define CHK 3125            // NE / 256 blocks
#define CAP 6144            // LDS staging capacity per bucket (mean 4082, std ~64)
#define NRT 1563            // ceil(NN/32) 32-row wave tiles

typedef __attribute__((ext_vector_type(8))) short short8v;
typedef __attribute__((ext_vector_type(4))) float f32x4;

// ---------------- init: zero bucket counts + pooled accumulators ----------------
__global__ void k_init(int* __restrict__ bcnt, float* __restrict__ pooled) {
  int i = blockIdx.x * blockDim.x + threadIdx.x;
  if (i < NBUK) bcnt[i] = 0;
  if (i < NB * FD) pooled[i] = 0.f;
}

// ---------------- bucket histogram (dst >> 8) ----------------
__global__ __launch_bounds__(256) void k_bhist(const int* __restrict__ dst,
                                               int* __restrict__ bcnt) {
  __shared__ int bh[NBUK];
  int t = threadIdx.x;
  for (int i = t; i < NBUK; i += 256) bh[i] = 0;
  __syncthreads();
  int e0 = blockIdx.x * CHK, e1 = e0 + CHK;
  if (e1 > NE) e1 = NE;
  for (int e = e0 + t; e < e1; e += 256) atomicAdd(&bh[dst[e] >> 8], 1);
  __syncthreads();
  for (int i = t; i < NBUK; i += 256) if (bh[i]) atomicAdd(&bcnt[i], bh[i]);
}

// ---------------- scan of 196 bucket counts ----------------
__global__ __launch_bounds__(256) void k_bscan(const int* __restrict__ bcnt,
                                               int* __restrict__ bbase,
                                               int* __restrict__ bcur) {
  __shared__ int wsum[4];
  int t = threadIdx.x;
  int v = (t < NBUK) ? bcnt[t] : 0;
  int lane = t & 63, wv = t >> 6;
  int s = v;
  #pragma unroll
  for (int off = 1; off < 64; off <<= 1) {
    int y = __shfl_up(s, off, 64);
    if (lane >= off) s += y;
  }
  if (lane == 63) wsum[wv] = s;
  __syncthreads();
  if (t == 0) {
    int r = 0;
    #pragma unroll
    for (int i = 0; i < 4; ++i) { int x = wsum[i]; wsum[i] = r; r += x; }
  }
  __syncthreads();
  int excl = s - v + wsum[wv];
  if (t < NBUK) { bbase[t] = excl; bcur[t] = excl; }
  if (t == NBUK - 1) bbase[NBUK] = excl + v;
}

// ---------------- bucketed scatter: edges -> bucket-ordered packed list ----------------
// pkt = (src << 8) | (dst & 255)
__global__ __launch_bounds__(256) void k_bscatter(const int* __restrict__ src,
    const int* __restrict__ dst, int* __restrict__ bcur, int* __restrict__ tmpv) {
  __shared__ int bh[NBUK];
  __shared__ int bb[NBUK];
  __shared__ int brun[NBUK];
  int t = threadIdx.x;
  int e0 = blockIdx.x * CHK, e1 = e0 + CHK;
  if (e1 > NE) e1 = NE;
  for (int i = t; i < NBUK; i += 256) { bh[i] = 0; brun[i] = 0; }
  __syncthreads();
  for (int e = e0 + t; e < e1; e += 256) atomicAdd(&bh[dst[e] >> 8], 1);
  __syncthreads();
  for (int i = t; i < NBUK; i += 256)
    bb[i] = bh[i] ? atomicAdd(&bcur[i], bh[i]) : 0;
  __syncthreads();
  for (int e = e0 + t; e < e1; e += 256) {
    int d = dst[e];
    int bk = d >> 8;
    int p = bb[bk] + atomicAdd(&brun[bk], 1);
    tmpv[p] = (src[e] << 8) | (d & 255);
  }
}

// ---------------- per-bucket CSR finalize: offs + sorted ssrc, all in LDS ----------------
__global__ __launch_bounds__(256) void k_bcsr(const int* __restrict__ tmpv,
    const int* __restrict__ bbase, int* __restrict__ offs, int* __restrict__ ssrc) {
  __shared__ int sdeg[256];
  __shared__ int scur[256];
  __shared__ int wsum[4];
  __shared__ int lsrc[CAP];
  int b = blockIdx.x, t = threadIdx.x;
  int es = bbase[b], ee = bbase[b + 1];
  int cnt = ee - es;
  sdeg[t] = 0;
  __syncthreads();
  for (int i = t; i < cnt; i += 256) atomicAdd(&sdeg[tmpv[es + i] & 255], 1);
  __syncthreads();
  int v = sdeg[t];
  int lane = t & 63, wv = t >> 6;
  int s = v;
  #pragma unroll
  for (int off = 1; off < 64; off <<= 1) {
    int y = __shfl_up(s, off, 64);
    if (lane >= off) s += y;
  }
  if (lane == 63) wsum[wv] = s;
  __syncthreads();
  if (t == 0) {
    int r = 0;
    #pragma unroll
    for (int i = 0; i < 4; ++i) { int x = wsum[i]; wsum[i] = r; r += x; }
  }
  __syncthreads();
  int excl = s - v + wsum[wv];
  scur[t] = excl;
  int node = b * 256 + t;
  if (node < NN) offs[node] = es + excl;
  if (b == NBUK - 1 && t == 0) offs[NN] = NE;
  __syncthreads();
  if (cnt <= CAP) {
    for (int i = t; i < cnt; i += 256) {
      int pkt = tmpv[es + i];
      int p = atomicAdd(&scur[pkt & 255], 1);
      lsrc[p] = pkt >> 8;
    }
    __syncthreads();
    for (int i = t; i < cnt; i += 256) ssrc[es + i] = lsrc[i];
  } else {  // statistically impossible fallback, kept for safety
    for (int i = t; i < cnt; i += 256) {
      int pkt = tmpv[es + i];
      int p = atomicAdd(&scur[pkt & 255], 1);
      ssrc[es + p] = pkt >> 8;
    }
  }
}

// ---------------- bf16 helpers ----------------
__device__ __forceinline__ unsigned short f2bf(float f) {
  unsigned u = __float_as_uint(f);
  u += 0x7fffu + ((u >> 16) & 1);          // RNE
  return (unsigned short)(u >> 16);
}
__device__ __forceinline__ float bfh2f(unsigned short h) {
  return __uint_as_float(((unsigned)h) << 16);
}

// ---------------- pre-split + pre-swizzle the 5 weight matrices ----------------
// Image per matrix: [row*128 + 8*(slot ^ (row&15))], slot = k>>3 (16 slots of 8).
// Conflict-free for the GEMM's 16-row fragment-column ds_read_b128 pattern.
__global__ __launch_bounds__(256) void k_wprep(const float* __restrict__ W0,
    const float* __restrict__ W1, const float* __restrict__ W2,
    const float* __restrict__ W3, const float* __restrict__ W4,
    unsigned short* __restrict__ wh, unsigned short* __restrict__ wl) {
  int id = blockIdx.x * 256 + threadIdx.x;
  if (id >= 5 * 2048) return;
  int w = id >> 11, rem = id & 2047;
  int row = rem >> 4, slot = rem & 15;
  const float* Wp = (w == 0) ? W0 : (w == 1) ? W1 : (w == 2) ? W2 : (w == 3) ? W3 : W4;
  const float* sp = &Wp[row * 128 + slot * 8];
  size_t dst = (size_t)w * 16384 + row * 128 + 8 * (slot ^ (row & 15));
  short8v hi, lo;
  #pragma unroll
  for (int j = 0; j < 8; ++j) {
    float f = sp[j];
    unsigned short h = f2bf(f);
    hi[j] = (short)h;
    lo[j] = (short)f2bf(f - bfh2f(h));
  }
  *(short8v*)&wh[dst] = hi;
  *(short8v*)&wl[dst] = lo;
}

// ---------------- MFMA linear, W-resident in LDS, barrier-free main loop ------------
// Block = 512 threads (8 waves). Full W hi/lo (64 KB) staged once; then each wave
// owns col-half (wv&1) and grid-strides over 32-row tiles, loading A fragments
// directly global->reg with in-register hi/lo split. 3 MFMA per K-slice, fp32 acc.
// blockIdx.y selects the matrix; 2 blocks/CU (128 KB LDS).
__global__ __launch_bounds__(512, 4) void k_lingemm(const float* __restrict__ in,
    const unsigned short* __restrict__ wh_img, const unsigned short* __restrict__ wl_img,
    int wbase,
    const float* __restrict__ b0, const float* __restrict__ b1, const float* __restrict__ b2,
    unsigned short* __restrict__ o0, unsigned short* __restrict__ o1,
    float* __restrict__ o2, int nrows) {
  __shared__ unsigned short s_wh[128 * 128];   // 32 KB
  __shared__ unsigned short s_wl[128 * 128];   // 32 KB
  const int w = blockIdx.y;
  const int tid = threadIdx.x;
  const int lane = tid & 63;
  const int wv = tid >> 6;          // 0..7
  const int nh = wv & 1;            // col half
  const int rq = wv >> 1;           // 0..3
  const int n0 = nh * 64;
  const int g = lane >> 4, lr = lane & 15;

  // stage full W hi/lo: pure 16B copies from pre-swizzled image
  {
    const unsigned short* sh = wh_img + (size_t)(wbase + w) * 16384;
    const unsigned short* sl = wl_img + (size_t)(wbase + w) * 16384;
    #pragma unroll
    for (int i = 0; i < 4; ++i) {
      int c = (i * 512 + tid) * 8;
      *(short8v*)&s_wh[c] = *(const short8v*)&sh[c];
      *(short8v*)&s_wl[c] = *(const short8v*)&sl[c];
    }
  }
  __syncthreads();

  const float* bp = (w == 0) ? b0 : (w == 1) ? b1 : b2;
  float bv[4];
  #pragma unroll
  for (int nt = 0; nt < 4; ++nt) bv[nt] = bp[n0 + nt * 16 + lr];

  for (int rt = blockIdx.x * 4 + rq; rt < NRT; rt += gridDim.x * 4) {
    const int m0 = rt * 32;
    f32x4 acc[2][4];
    #pragma unroll
    for (int mt = 0; mt < 2; ++mt)
      #pragma unroll
      for (int nt = 0; nt < 4; ++nt)
        acc[mt][nt] = (f32x4){0.f, 0.f, 0.f, 0.f};

    int arow[2];
    #pragma unroll
    for (int mt = 0; mt < 2; ++mt) {
      int r = m0 + mt * 16 + lr;
      arow[mt] = (r < nrows) ? r : (nrows - 1);   // clamp; stores are guarded
    }

    #pragma unroll
    for (int ks = 0; ks < 4; ++ks) {
      const int k0 = ks * 32 + g * 8;
      short8v ah[2], al[2];
      #pragma unroll
      for (int mt = 0; mt < 2; ++mt) {
        const float* ap = &in[(size_t)arow[mt] * 128 + k0];
        float4 a0 = *(const float4*)ap;
        float4 a1 = *(const float4*)(ap + 4);
        float f[8] = {a0.x, a0.y, a0.z, a0.w, a1.x, a1.y, a1.z, a1.w};
        #pragma unroll
        for (int j = 0; j < 8; ++j) {
          unsigned short h = f2bf(f[j]);
          ah[mt][j] = (short)h;
          al[mt][j] = (short)f2bf(f[j] - bfh2f(h));
        }
      }
      #pragma unroll
      for (int nt = 0; nt < 4; ++nt) {
        int row = n0 + nt * 16 + lr;
        int idx = row * 128 + 8 * ((ks * 4 + g) ^ (row & 15));
        short8v bh = *(const short8v*)&s_wh[idx];
        short8v bl = *(const short8v*)&s_wl[idx];
        #pragma unroll
        for (int mt = 0; mt < 2; ++mt) {
          acc[mt][nt] = __builtin_amdgcn_mfma_f32_16x16x32_bf16(ah[mt], bh, acc[mt][nt], 0, 0, 0);
          acc[mt][nt] = __builtin_amdgcn_mfma_f32_16x16x32_bf16(ah[mt], bl, acc[mt][nt], 0, 0, 0);
          acc[mt][nt] = __builtin_amdgcn_mfma_f32_16x16x32_bf16(al[mt], bh, acc[mt][nt], 0, 0, 0);
        }
      }
    }
    // epilogue: D row = 4*g + i, col = lr within each 16x16 tile
    #pragma unroll
    for (int nt = 0; nt < 4; ++nt)
      #pragma unroll
      for (int mt = 0; mt < 2; ++mt)
        #pragma unroll
        for (int i = 0; i < 4; ++i) {
          int r = m0 + mt * 16 + 4 * g + i;
          if (r < nrows) {
            float vv = acc[mt][nt][i] + bv[nt];
            size_t o = (size_t)r * 128 + n0 + nt * 16 + lr;
            if (w == 2) o2[o] = vv;
            else if (w == 1) o1[o] = f2bf(vv);
            else o0[o] = f2bf(vv);
          }
        }
  }
}

__device__ __forceinline__ float lrelu(float x) { return x > 0.f ? x : 0.2f * x; }

// ---------------- GATv2: bf16 gathers, no-max softmax (|s| <= ~2), 4-wide MLP ----
__global__ __launch_bounds__(256) void k_gat(const unsigned short* __restrict__ xl,
    const unsigned short* __restrict__ xr, const int* __restrict__ offs,
    const int* __restrict__ ssrc, const float* __restrict__ att,
    const float* __restrict__ bias, const float* __restrict__ resid,
    float* __restrict__ out) {
  int grp = threadIdx.x >> 5;
  int lane = threadIdx.x & 31;
  int n = blockIdx.x * 8 + grp;
  if (n >= NN) return;
  float4 att4 = ((const float4*)att)[lane];
  ushort4 xu = ((const ushort4*)xr)[(size_t)n * 32 + lane];
  float4 xr4 = make_float4(bfh2f(xu.x), bfh2f(xu.y), bfh2f(xu.z), bfh2f(xu.w));
  int e0 = offs[n], e1 = offs[n + 1];
  float den = 0.f;
  float4 acc = make_float4(0.f, 0.f, 0.f, 0.f);
  int e = e0;
  for (; e + 3 < e1; e += 4) {
    ushort4 u[4];
    #pragma unroll
    for (int j = 0; j < 4; ++j) {
      int s = ssrc[e + j];
      u[j] = ((const ushort4*)xl)[(size_t)s * 32 + lane];
    }
    #pragma unroll
    for (int j = 0; j < 4; ++j) {
      float4 v = make_float4(bfh2f(u[j].x), bfh2f(u[j].y), bfh2f(u[j].z), bfh2f(u[j].w));
      float p = lrelu(v.x + xr4.x) * att4.x + lrelu(v.y + xr4.y) * att4.y +
                lrelu(v.z + xr4.z) * att4.z + lrelu(v.w + xr4.w) * att4.w;
      p += __shfl_xor(p, 1, 64); p += __shfl_xor(p, 2, 64); p += __shfl_xor(p, 4, 64);
      float w = __expf(p);
      den += w;
      acc.x += w * v.x; acc.y += w * v.y; acc.z += w * v.z; acc.w += w * v.w;
    }
  }
  for (; e < e1; ++e) {
    int s = ssrc[e];
    ushort4 u0 = ((const ushort4*)xl)[(size_t)s * 32 + lane];
    float4 v = make_float4(bfh2f(u0.x), bfh2f(u0.y), bfh2f(u0.z), bfh2f(u0.w));
    float p = lrelu(v.x + xr4.x) * att4.x + lrelu(v.y + xr4.y) * att4.y +
              lrelu(v.z + xr4.z) * att4.z + lrelu(v.w + xr4.w) * att4.w;
    p += __shfl_xor(p, 1, 64); p += __shfl_xor(p, 2, 64); p += __shfl_xor(p, 4, 64);
    float w = __expf(p);
    den += w;
    acc.x += w * v.x; acc.y += w * v.y; acc.z += w * v.z; acc.w += w * v.w;
  }
  float inv = (den > 0.f) ? 1.f / den : 0.f;
  float4 b4 = ((const float4*)bias)[lane];
  float4 r4 = ((const float4*)resid)[(size_t)n * 32 + lane];
  float4 o;
  o.x = fmaxf(acc.x * inv + b4.x, 0.f) + r4.x;
  o.y = fmaxf(acc.y * inv + b4.y, 0.f) + r4.y;
  o.z = fmaxf(acc.z * inv + b4.z, 0.f) + r4.z;
  o.w = fmaxf(acc.w * inv + b4.w, 0.f) + r4.w;
  ((float4*)out)[(size_t)n * 32 + lane] = o;
}

// ---------------- mean-pool over sorted batch, run-length-compressed atomics ----------------
__global__ __launch_bounds__(256) void k_pool(const float* __restrict__ h,
    const int* __restrict__ batch, float* __restrict__ pooled) {
  int col = threadIdx.x & 127;
  int ro = threadIdx.x >> 7;
  int n0 = blockIdx.x * 128;
  float rs = 0.f;
  int cb = -1;
  for (int i = ro; i < 128; i += 2) {
    int n = n0 + i;
    if (n >= NN) break;
    int bb = batch[n];
    if (bb != cb) {
      if (cb >= 0) atomicAdd(&pooled[cb * FD + col], rs);
      rs = 0.f; cb = bb;
    }
    rs += h[(size_t)n * FD + col];
  }
  if (cb >= 0) atomicAdd(&pooled[cb * FD + col], rs);
}

// ---------------- MLP head: one block per graph ----------------
__global__ __launch_bounds__(128) void k_mlp(const float* __restrict__ pooled,
    const int* __restrict__ batch, const float* __restrict__ domain,
    const float* __restrict__ Wg, const float* __restrict__ bg,
    const float* __restrict__ Wd, const float* __restrict__ bd,
    const float* __restrict__ Wf1, const float* __restrict__ bf1,
    const float* __restrict__ Wf2, const float* __restrict__ bf2,
    const float* __restrict__ Wf3, const float* __restrict__ bf3,
    float* __restrict__ out) {
  __shared__ float z[192];
  __shared__ float z1[128];
  __shared__ float z2[64];
  __shared__ float pm[128];
  __shared__ int cnt;
  int b = blockIdx.x, t = threadIdx.x;
  if (t == 0) {
    int lo = 0, hi = NN;
    while (lo < hi) { int mid = (lo + hi) >> 1; if (batch[mid] < b) lo = mid + 1; else hi = mid; }
    int lb = lo; lo = 0; hi = NN;
    while (lo < hi) { int mid = (lo + hi) >> 1; if (batch[mid] < b + 1) lo = mid + 1; else hi = mid; }
    cnt = lo - lb;
  }
  __syncthreads();
  float invc = 1.f / fmaxf((float)cnt, 1.f);
  pm[t] = pooled[b * FD + t] * invc;
  __syncthreads();
  {
    float a = bg[t];
    for (int k = 0; k < 128; ++k) a += pm[k] * Wg[t * 128 + k];
    z[t] = fmaxf(a, 0.f);
  }
  if (t < 64) {
    float a = bd[t];
    for (int k = 0; k < 32; ++k) a += domain[b * 32 + k] * Wd[t * 32 + k];
    z[128 + t] = fmaxf(a, 0.f);
  }
  __syncthreads();
  {
    float a = bf1[t];
    for (int k = 0; k < 192; ++k) a += z[k] * Wf1[t * 192 + k];
    z1[t] = fmaxf(a, 0.f);
  }
  __syncthreads();
  if (t < 64) {
    float a = bf2[t];
    for (int k = 0; k < 128; ++k) a += z1[k] * Wf2[t * 128 + k];
    z2[t] = fmaxf(a, 0.f);
  }
  __syncthreads();
  if (t < 64) {
    float v = z2[t] * Wf3[t];
    for (int off = 1; off < 64; off <<= 1) v += __shfl_xor(v, off, 64);
    if (t == 0) out[b] = v + bf3[0];
  }
}

extern "C" void kernel_launch(void* const* d_in, const int* in_sizes, int n_in,
                              void* d_out, int out_size, void* d_ws, size_t ws_size,
                              hipStream_t stream) {
  const float* x      = (const float*)d_in[0];
  const float* domain = (const float*)d_in[1];
  const float* Wl1 = (const float*)d_in[2];  const float* bl1 = (const float*)d_in[3];
  const float* Wr1 = (const float*)d_in[4];  const float* br1 = (const float*)d_in[5];
  const float* att1= (const float*)d_in[6];  const float* bias1=(const float*)d_in[7];
  const float* Wl2 = (const float*)d_in[8];  const float* bl2 = (const float*)d_in[9];
  const float* Wr2 = (const float*)d_in[10]; const float* br2 = (const float*)d_in[11];
  const float* att2= (const float*)d_in[12]; const float* bias2=(const float*)d_in[13];
  const float* Wres= (const float*)d_in[14]; const float* bres= (const float*)d_in[15];
  const float* Wd  = (const float*)d_in[16]; const float* bd  = (const float*)d_in[17];
  const float* Wg  = (const float*)d_in[18]; const float* bg  = (const float*)d_in[19];
  const float* Wf1 = (const float*)d_in[20]; const float* bf1 = (const float*)d_in[21];
  const float* Wf2 = (const float*)d_in[22]; const float* bf2 = (const float*)d_in[23];
  const float* Wf3 = (const float*)d_in[24]; const float* bf3 = (const float*)d_in[25];
  const int* ei    = (const int*)d_in[26];
  const int* batch = (const int*)d_in[27];
  const int* esrc = ei;
  const int* edst = ei + NE;
  float* outp = (float*)d_out;

  char* p = (char*)d_ws;
  auto carve = [&](size_t bytes) { char* r = p; p += (bytes + 255) & ~(size_t)255; return r; };
  int* bcnt     = (int*)carve((size_t)NBUK * 4);
  int* bbase    = (int*)carve((size_t)(NBUK + 1) * 4);
  int* bcur     = (int*)carve((size_t)NBUK * 4);
  int* tmpv     = (int*)carve((size_t)NE * 4);
  int* ssrc     = (int*)carve((size_t)NE * 4);
  int* offs     = (int*)carve((size_t)(NN + 1) * 4);
  unsigned short* wh = (unsigned short*)carve((size_t)5 * 16384 * 2);
  unsigned short* wl = (unsigned short*)carve((size_t)5 * 16384 * 2);
  unsigned short* xl = (unsigned short*)carve((size_t)NN * FD * 2);
  unsigned short* xr = (unsigned short*)carve((size_t)NN * FD * 2);
  float* res    = (float*)carve((size_t)NN * FD * 4);
  float* h1     = (float*)carve((size_t)NN * FD * 4);
  float* pooled = (float*)carve((size_t)NB * FD * 4);
  float* h2 = res;   // res dead after first GAT; alias

  dim3 b256(256);
  hipLaunchKernelGGL(k_init, dim3((NB * FD + 255) / 256), b256, 0, stream, bcnt, pooled);
  hipLaunchKernelGGL(k_wprep, dim3(40), b256, 0, stream, Wl1, Wr1, Wres, Wl2, Wr2, wh, wl);
  hipLaunchKernelGGL(k_bhist, dim3(256), b256, 0, stream, edst, bcnt);
  hipLaunchKernelGGL(k_bscan, dim3(1), b256, 0, stream, bcnt, bbase, bcur);
  hipLaunchKernelGGL(k_bscatter, dim3(256), b256, 0, stream, esrc, edst, bcur, tmpv);
  hipLaunchKernelGGL(k_bcsr, dim3(NBUK), b256, 0, stream, tmpv, bbase, offs, ssrc);

  // layer 1: {xl, xr, res} — blockIdx.y = matrix, 510 blocks total (~2/CU)
  hipLaunchKernelGGL(k_lingemm, dim3(170, 3), dim3(512), 0, stream,
                     x, wh, wl, 0, bl1, br1, bres, xl, xr, res, NN);
  hipLaunchKernelGGL(k_gat, dim3((NN + 7) / 8), b256, 0, stream, xl, xr, offs, ssrc, att1, bias1, res, h1);
  // layer 2: {xl, xr} — 512 blocks total
  hipLaunchKernelGGL(k_lingemm, dim3(256, 2), dim3(512), 0, stream,
                     h1, wh, wl, 3, bl2, br2, (const float*)nullptr, xl, xr, (float*)nullptr, NN);
  hipLaunchKernelGGL(k_gat, dim3((NN + 7) / 8), b256, 0, stream, xl, xr, offs, ssrc, att2, bias2, h1, h2);
  hipLaunchKernelGGL(k_pool, dim3((NN + 127) / 128), b256, 0, stream, h2, batch, pooled);
  hipLaunchKernelGGL(k_mlp, dim3(NB), dim3(128), 0, stream, pooled, batch, domain,
                     Wg, bg, Wd, bd, Wf1, bf1, Wf2, bf2, Wf3, bf3, outp);
}

// Round 9
// 260.936 us; speedup vs baseline: 1.3826x; 1.3826x over previous
//
#include <hip/hip_runtime.h>
#include <math.h>

#define NN 50000
#define NE 800000
#define FD 128      // IN == HC == 128
#define NB 64
#define NBUK 196            // ceil(NN/256) buckets of 256 dst nodes
#define CHK 3125            // NE / 256 blocks
#define CAP 6144            // LDS staging capacity per bucket (mean 4082, std ~64)
#define NBLK 782            // ceil(NN/64) 64-row tiles for the linears

typedef __attribute__((ext_vector_type(8))) short short8v;
typedef __attribute__((ext_vector_type(4))) float f32x4;

// ---------------- init: zero bucket counts + pooled accumulators ----------------
__global__ void k_init(int* __restrict__ bcnt, float* __restrict__ pooled) {
  int i = blockIdx.x * blockDim.x + threadIdx.x;
  if (i < NBUK) bcnt[i] = 0;
  if (i < NB * FD) pooled[i] = 0.f;
}

// ---------------- bucket histogram (dst >> 8) ----------------
__global__ __launch_bounds__(256) void k_bhist(const int* __restrict__ dst,
                                               int* __restrict__ bcnt) {
  __shared__ int bh[NBUK];
  int t = threadIdx.x;
  for (int i = t; i < NBUK; i += 256) bh[i] = 0;
  __syncthreads();
  int e0 = blockIdx.x * CHK, e1 = e0 + CHK;
  if (e1 > NE) e1 = NE;
  for (int e = e0 + t; e < e1; e += 256) atomicAdd(&bh[dst[e] >> 8], 1);
  __syncthreads();
  for (int i = t; i < NBUK; i += 256) if (bh[i]) atomicAdd(&bcnt[i], bh[i]);
}

// ---------------- scan of 196 bucket counts ----------------
__global__ __launch_bounds__(256) void k_bscan(const int* __restrict__ bcnt,
                                               int* __restrict__ bbase,
                                               int* __restrict__ bcur) {
  __shared__ int wsum[4];
  int t = threadIdx.x;
  int v = (t < NBUK) ? bcnt[t] : 0;
  int lane = t & 63, wv = t >> 6;
  int s = v;
  #pragma unroll
  for (int off = 1; off < 64; off <<= 1) {
    int y = __shfl_up(s, off, 64);
    if (lane >= off) s += y;
  }
  if (lane == 63) wsum[wv] = s;
  __syncthreads();
  if (t == 0) {
    int r = 0;
    #pragma unroll
    for (int i = 0; i < 4; ++i) { int x = wsum[i]; wsum[i] = r; r += x; }
  }
  __syncthreads();
  int excl = s - v + wsum[wv];
  if (t < NBUK) { bbase[t] = excl; bcur[t] = excl; }
  if (t == NBUK - 1) bbase[NBUK] = excl + v;
}

// ---------------- bucketed scatter: edges -> bucket-ordered packed list ----------------
// pkt = (src << 8) | (dst & 255)
__global__ __launch_bounds__(256) void k_bscatter(const int* __restrict__ src,
    const int* __restrict__ dst, int* __restrict__ bcur, int* __restrict__ tmpv) {
  __shared__ int bh[NBUK];
  __shared__ int bb[NBUK];
  __shared__ int brun[NBUK];
  int t = threadIdx.x;
  int e0 = blockIdx.x * CHK, e1 = e0 + CHK;
  if (e1 > NE) e1 = NE;
  for (int i = t; i < NBUK; i += 256) { bh[i] = 0; brun[i] = 0; }
  __syncthreads();
  for (int e = e0 + t; e < e1; e += 256) atomicAdd(&bh[dst[e] >> 8], 1);
  __syncthreads();
  for (int i = t; i < NBUK; i += 256)
    bb[i] = bh[i] ? atomicAdd(&bcur[i], bh[i]) : 0;
  __syncthreads();
  for (int e = e0 + t; e < e1; e += 256) {
    int d = dst[e];
    int bk = d >> 8;
    int p = bb[bk] + atomicAdd(&brun[bk], 1);
    tmpv[p] = (src[e] << 8) | (d & 255);
  }
}

// ---------------- per-bucket CSR finalize: offs + sorted ssrc, all in LDS ----------------
__global__ __launch_bounds__(256) void k_bcsr(const int* __restrict__ tmpv,
    const int* __restrict__ bbase, int* __restrict__ offs, int* __restrict__ ssrc) {
  __shared__ int sdeg[256];
  __shared__ int scur[256];
  __shared__ int wsum[4];
  __shared__ int lsrc[CAP];
  int b = blockIdx.x, t = threadIdx.x;
  int es = bbase[b], ee = bbase[b + 1];
  int cnt = ee - es;
  sdeg[t] = 0;
  __syncthreads();
  for (int i = t; i < cnt; i += 256) atomicAdd(&sdeg[tmpv[es + i] & 255], 1);
  __syncthreads();
  int v = sdeg[t];
  int lane = t & 63, wv = t >> 6;
  int s = v;
  #pragma unroll
  for (int off = 1; off < 64; off <<= 1) {
    int y = __shfl_up(s, off, 64);
    if (lane >= off) s += y;
  }
  if (lane == 63) wsum[wv] = s;
  __syncthreads();
  if (t == 0) {
    int r = 0;
    #pragma unroll
    for (int i = 0; i < 4; ++i) { int x = wsum[i]; wsum[i] = r; r += x; }
  }
  __syncthreads();
  int excl = s - v + wsum[wv];
  scur[t] = excl;
  int node = b * 256 + t;
  if (node < NN) offs[node] = es + excl;
  if (b == NBUK - 1 && t == 0) offs[NN] = NE;
  __syncthreads();
  if (cnt <= CAP) {
    for (int i = t; i < cnt; i += 256) {
      int pkt = tmpv[es + i];
      int p = atomicAdd(&scur[pkt & 255], 1);
      lsrc[p] = pkt >> 8;
    }
    __syncthreads();
    for (int i = t; i < cnt; i += 256) ssrc[es + i] = lsrc[i];
  } else {  // statistically impossible fallback, kept for safety
    for (int i = t; i < cnt; i += 256) {
      int pkt = tmpv[es + i];
      int p = atomicAdd(&scur[pkt & 255], 1);
      ssrc[es + p] = pkt >> 8;
    }
  }
}

// ---------------- bf16 helpers ----------------
__device__ __forceinline__ unsigned short f2bf(float f) {
  unsigned u = __float_as_uint(f);
  u += 0x7fffu + ((u >> 16) & 1);          // RNE
  return (unsigned short)(u >> 16);
}
__device__ __forceinline__ float bfh2f(unsigned short h) {
  return __uint_as_float(((unsigned)h) << 16);
}

// ---------------- pre-split + pre-swizzle the 5 weight matrices ----------------
// Image layout per (w, kh): [row*64 + 8*((slot&7) ^ (row&7))], ready for LDS memcpy.
__global__ __launch_bounds__(256) void k_wprep(const float* __restrict__ W0,
    const float* __restrict__ W1, const float* __restrict__ W2,
    const float* __restrict__ W3, const float* __restrict__ W4,
    unsigned short* __restrict__ wh, unsigned short* __restrict__ wl) {
  int id = blockIdx.x * 256 + threadIdx.x;
  if (id >= 5 * 2048) return;
  int w = id >> 11, rem = id & 2047;
  int row = rem >> 4, slot = rem & 15;
  const float* Wp = (w == 0) ? W0 : (w == 1) ? W1 : (w == 2) ? W2 : (w == 3) ? W3 : W4;
  const float* sp = &Wp[row * 128 + slot * 8];
  int kh = slot >> 3, s7 = slot & 7;
  int dst = ((w * 2 + kh) * 8192) + row * 64 + 8 * (s7 ^ (row & 7));
  short8v hi, lo;
  #pragma unroll
  for (int j = 0; j < 8; ++j) {
    float f = sp[j];
    unsigned short h = f2bf(f);
    hi[j] = (short)h;
    lo[j] = (short)f2bf(f - bfh2f(h));
  }
  *(short8v*)&wh[dst] = hi;
  *(short8v*)&wl[dst] = lo;
}

// ---------------- pre-pack x into the swizzled hi/lo A-image ----------------
// Per 64-row blk: [kh0 hi 8KB][kh0 lo 8KB][kh1 hi 8KB][kh1 lo 8KB] (16384 shorts).
__global__ __launch_bounds__(256) void k_xprep(const float* __restrict__ x,
                                               unsigned short* __restrict__ ximg) {
  int id = blockIdx.x * 256 + threadIdx.x;
  if (id >= NN * 16) return;
  int row = id >> 4, slot = id & 15;
  const float* sp = &x[(size_t)row * 128 + slot * 8];
  int blk = row >> 6, lrow = row & 63, kh = slot >> 3, s7 = slot & 7;
  size_t hoff = (size_t)blk * 16384 + kh * 8192 + lrow * 64 + 8 * (s7 ^ (lrow & 7));
  short8v hi, lo;
  #pragma unroll
  for (int j = 0; j < 8; ++j) {
    float f = sp[j];
    unsigned short h = f2bf(f);
    hi[j] = (short)h;
    lo[j] = (short)f2bf(f - bfh2f(h));
  }
  *(short8v*)&ximg[hoff] = hi;
  *(short8v*)&ximg[hoff + 4096] = lo;
}

// ---------------- MFMA linear: LDS-staged from prepacked images, 8 waves ------------
// blockIdx.y = matrix, blockIdx.x = 64-row tile. Block 512 threads (8 waves, 2x4),
// wave tile 32x32. All staging = pure 16B copies (A image + W image pre-swizzled,
// pre-split hi/lo). 3 MFMA per K-slice (hi*hi + hi*lo + lo*hi), fp32 acc. LDS 48 KB.
__global__ __launch_bounds__(512, 6) void k_linm2(
    const unsigned short* __restrict__ aimg,
    const unsigned short* __restrict__ wh_img, const unsigned short* __restrict__ wl_img,
    int wbase,
    const float* __restrict__ b0, const float* __restrict__ b1, const float* __restrict__ b2,
    unsigned short* __restrict__ o0, unsigned short* __restrict__ o1,
    float* __restrict__ o2, int nrows) {
  __shared__ unsigned short s_a[8192];    // 16 KB: hi [0,4096) lo [4096,8192)
  __shared__ unsigned short s_wh[8192];   // 16 KB
  __shared__ unsigned short s_wl[8192];   // 16 KB
  const int w = blockIdx.y;
  const int blk = blockIdx.x;
  const int tid = threadIdx.x;
  const int lane = tid & 63;
  const int wv = tid >> 6;            // 0..7
  const int m0 = (wv >> 2) * 32;      // wave row
  const int n0 = (wv & 3) * 32;       // wave col
  const int rbase = blk * 64;
  const int g = lane >> 4, lr = lane & 15;

  f32x4 acc[2][2];
  #pragma unroll
  for (int mt = 0; mt < 2; ++mt)
    #pragma unroll
    for (int nt = 0; nt < 2; ++nt)
      acc[mt][nt] = (f32x4){0.f, 0.f, 0.f, 0.f};

  for (int kh = 0; kh < 2; ++kh) {
    if (kh) __syncthreads();
    // A half: 16 KB contiguous copy from image
    {
      const short8v* asrc = (const short8v*)(aimg + (size_t)blk * 16384 + kh * 8192);
      short8v* adst = (short8v*)s_a;
      adst[tid] = asrc[tid];
      adst[512 + tid] = asrc[512 + tid];
    }
    // W half: 16+16 KB pure copies
    {
      const short8v* whs = (const short8v*)(wh_img + (size_t)((wbase + w) * 2 + kh) * 8192);
      const short8v* wls = (const short8v*)(wl_img + (size_t)((wbase + w) * 2 + kh) * 8192);
      short8v* whd = (short8v*)s_wh;
      short8v* wld = (short8v*)s_wl;
      whd[tid] = whs[tid]; whd[512 + tid] = whs[512 + tid];
      wld[tid] = wls[tid]; wld[512 + tid] = wls[512 + tid];
    }
    __syncthreads();
    #pragma unroll
    for (int ks = 0; ks < 2; ++ks) {
      const int slot = ks * 4 + g;
      short8v ah[2], al[2];
      #pragma unroll
      for (int mt = 0; mt < 2; ++mt) {
        int row = m0 + mt * 16 + lr;
        int idx = row * 64 + 8 * (slot ^ (row & 7));
        ah[mt] = *(const short8v*)&s_a[idx];
        al[mt] = *(const short8v*)&s_a[idx + 4096];
      }
      #pragma unroll
      for (int nt = 0; nt < 2; ++nt) {
        int row2 = n0 + nt * 16 + lr;
        int idx2 = row2 * 64 + 8 * (slot ^ (row2 & 7));
        short8v bh = *(const short8v*)&s_wh[idx2];
        short8v bl = *(const short8v*)&s_wl[idx2];
        #pragma unroll
        for (int mt = 0; mt < 2; ++mt) {
          acc[mt][nt] = __builtin_amdgcn_mfma_f32_16x16x32_bf16(ah[mt], bh, acc[mt][nt], 0, 0, 0);
          acc[mt][nt] = __builtin_amdgcn_mfma_f32_16x16x32_bf16(ah[mt], bl, acc[mt][nt], 0, 0, 0);
          acc[mt][nt] = __builtin_amdgcn_mfma_f32_16x16x32_bf16(al[mt], bh, acc[mt][nt], 0, 0, 0);
        }
      }
    }
  }
  // epilogue: D row = 4*g + i, col = lr within each 16x16 tile
  const float* bp = (w == 0) ? b0 : (w == 1) ? b1 : b2;
  #pragma unroll
  for (int nt = 0; nt < 2; ++nt) {
    float bv = bp[n0 + nt * 16 + lr];
    #pragma unroll
    for (int mt = 0; mt < 2; ++mt)
      #pragma unroll
      for (int i = 0; i < 4; ++i) {
        int r = rbase + m0 + mt * 16 + 4 * g + i;
        if (r < nrows) {
          float vv = acc[mt][nt][i] + bv;
          size_t o = (size_t)r * 128 + n0 + nt * 16 + lr;
          if (w == 2) o2[o] = vv;
          else if (w == 1) o1[o] = f2bf(vv);
          else o0[o] = f2bf(vv);
        }
      }
  }
}

__device__ __forceinline__ float lrelu(float x) { return x > 0.f ? x : 0.2f * x; }

// ---------------- GATv2: bf16 gathers, no-max softmax, 4-wide MLP.
// Optionally also writes the swizzled hi/lo image of the output (for next GEMM).
__global__ __launch_bounds__(256) void k_gat(const unsigned short* __restrict__ xl,
    const unsigned short* __restrict__ xr, const int* __restrict__ offs,
    const int* __restrict__ ssrc, const float* __restrict__ att,
    const float* __restrict__ bias, const float* __restrict__ resid,
    float* __restrict__ out, unsigned short* __restrict__ himg) {
  int grp = threadIdx.x >> 5;
  int lane = threadIdx.x & 31;
  int n = blockIdx.x * 8 + grp;
  if (n >= NN) return;
  float4 att4 = ((const float4*)att)[lane];
  ushort4 xu = ((const ushort4*)xr)[(size_t)n * 32 + lane];
  float4 xr4 = make_float4(bfh2f(xu.x), bfh2f(xu.y), bfh2f(xu.z), bfh2f(xu.w));
  int e0 = offs[n], e1 = offs[n + 1];
  float den = 0.f;
  float4 acc = make_float4(0.f, 0.f, 0.f, 0.f);
  int e = e0;
  for (; e + 3 < e1; e += 4) {
    ushort4 u[4];
    #pragma unroll
    for (int j = 0; j < 4; ++j) {
      int s = ssrc[e + j];
      u[j] = ((const ushort4*)xl)[(size_t)s * 32 + lane];
    }
    #pragma unroll
    for (int j = 0; j < 4; ++j) {
      float4 v = make_float4(bfh2f(u[j].x), bfh2f(u[j].y), bfh2f(u[j].z), bfh2f(u[j].w));
      float p = lrelu(v.x + xr4.x) * att4.x + lrelu(v.y + xr4.y) * att4.y +
                lrelu(v.z + xr4.z) * att4.z + lrelu(v.w + xr4.w) * att4.w;
      p += __shfl_xor(p, 1, 64); p += __shfl_xor(p, 2, 64); p += __shfl_xor(p, 4, 64);
      float w = __expf(p);
      den += w;
      acc.x += w * v.x; acc.y += w * v.y; acc.z += w * v.z; acc.w += w * v.w;
    }
  }
  for (; e < e1; ++e) {
    int s = ssrc[e];
    ushort4 u0 = ((const ushort4*)xl)[(size_t)s * 32 + lane];
    float4 v = make_float4(bfh2f(u0.x), bfh2f(u0.y), bfh2f(u0.z), bfh2f(u0.w));
    float p = lrelu(v.x + xr4.x) * att4.x + lrelu(v.y + xr4.y) * att4.y +
              lrelu(v.z + xr4.z) * att4.z + lrelu(v.w + xr4.w) * att4.w;
    p += __shfl_xor(p, 1, 64); p += __shfl_xor(p, 2, 64); p += __shfl_xor(p, 4, 64);
    float w = __expf(p);
    den += w;
    acc.x += w * v.x; acc.y += w * v.y; acc.z += w * v.z; acc.w += w * v.w;
  }
  float inv = (den > 0.f) ? 1.f / den : 0.f;
  float4 b4 = ((const float4*)bias)[lane];
  float4 r4 = ((const float4*)resid)[(size_t)n * 32 + lane];
  float4 o;
  o.x = fmaxf(acc.x * inv + b4.x, 0.f) + r4.x;
  o.y = fmaxf(acc.y * inv + b4.y, 0.f) + r4.y;
  o.z = fmaxf(acc.z * inv + b4.z, 0.f) + r4.z;
  o.w = fmaxf(acc.w * inv + b4.w, 0.f) + r4.w;
  ((float4*)out)[(size_t)n * 32 + lane] = o;
  if (himg) {
    // image coords: cols c0=4*lane..+3 -> kh = lane>>4, slot = (lane>>1)&7, off = (lane&1)*4
    int lrow = n & 63, blk = n >> 6;
    int kh = lane >> 4, s7 = (lane >> 1) & 7, off4 = (lane & 1) * 4;
    size_t base = (size_t)blk * 16384 + kh * 8192 + lrow * 64 + 8 * (s7 ^ (lrow & 7)) + off4;
    ushort4 hi, lo;
    hi.x = f2bf(o.x); lo.x = f2bf(o.x - bfh2f(hi.x));
    hi.y = f2bf(o.y); lo.y = f2bf(o.y - bfh2f(hi.y));
    hi.z = f2bf(o.z); lo.z = f2bf(o.z - bfh2f(hi.z));
    hi.w = f2bf(o.w); lo.w = f2bf(o.w - bfh2f(hi.w));
    *(ushort4*)&himg[base] = hi;
    *(ushort4*)&himg[base + 4096] = lo;
  }
}

// ---------------- mean-pool over sorted batch, run-length-compressed atomics ----------------
__global__ __launch_bounds__(256) void k_pool(const float* __restrict__ h,
    const int* __restrict__ batch, float* __restrict__ pooled) {
  int col = threadIdx.x & 127;
  int ro = threadIdx.x >> 7;
  int n0 = blockIdx.x * 128;
  float rs = 0.f;
  int cb = -1;
  for (int i = ro; i < 128; i += 2) {
    int n = n0 + i;
    if (n >= NN) break;
    int bb = batch[n];
    if (bb != cb) {
      if (cb >= 0) atomicAdd(&pooled[cb * FD + col], rs);
      rs = 0.f; cb = bb;
    }
    rs += h[(size_t)n * FD + col];
  }
  if (cb >= 0) atomicAdd(&pooled[cb * FD + col], rs);
}

// ---------------- MLP head: one block per graph ----------------
__global__ __launch_bounds__(128) void k_mlp(const float* __restrict__ pooled,
    const int* __restrict__ batch, const float* __restrict__ domain,
    const float* __restrict__ Wg, const float* __restrict__ bg,
    const float* __restrict__ Wd, const float* __restrict__ bd,
    const float* __restrict__ Wf1, const float* __restrict__ bf1,
    const float* __restrict__ Wf2, const float* __restrict__ bf2,
    const float* __restrict__ Wf3, const float* __restrict__ bf3,
    float* __restrict__ out) {
  __shared__ float z[192];
  __shared__ float z1[128];
  __shared__ float z2[64];
  __shared__ float pm[128];
  __shared__ int cnt;
  int b = blockIdx.x, t = threadIdx.x;
  if (t == 0) {
    int lo = 0, hi = NN;
    while (lo < hi) { int mid = (lo + hi) >> 1; if (batch[mid] < b) lo = mid + 1; else hi = mid; }
    int lb = lo; lo = 0; hi = NN;
    while (lo < hi) { int mid = (lo + hi) >> 1; if (batch[mid] < b + 1) lo = mid + 1; else hi = mid; }
    cnt = lo - lb;
  }
  __syncthreads();
  float invc = 1.f / fmaxf((float)cnt, 1.f);
  pm[t] = pooled[b * FD + t] * invc;
  __syncthreads();
  {
    float a = bg[t];
    for (int k = 0; k < 128; ++k) a += pm[k] * Wg[t * 128 + k];
    z[t] = fmaxf(a, 0.f);
  }
  if (t < 64) {
    float a = bd[t];
    for (int k = 0; k < 32; ++k) a += domain[b * 32 + k] * Wd[t * 32 + k];
    z[128 + t] = fmaxf(a, 0.f);
  }
  __syncthreads();
  {
    float a = bf1[t];
    for (int k = 0; k < 192; ++k) a += z[k] * Wf1[t * 192 + k];
    z1[t] = fmaxf(a, 0.f);
  }
  __syncthreads();
  if (t < 64) {
    float a = bf2[t];
    for (int k = 0; k < 128; ++k) a += z1[k] * Wf2[t * 128 + k];
    z2[t] = fmaxf(a, 0.f);
  }
  __syncthreads();
  if (t < 64) {
    float v = z2[t] * Wf3[t];
    for (int off = 1; off < 64; off <<= 1) v += __shfl_xor(v, off, 64);
    if (t == 0) out[b] = v + bf3[0];
  }
}

extern "C" void kernel_launch(void* const* d_in, const int* in_sizes, int n_in,
                              void* d_out, int out_size, void* d_ws, size_t ws_size,
                              hipStream_t stream) {
  const float* x      = (const float*)d_in[0];
  const float* domain = (const float*)d_in[1];
  const float* Wl1 = (const float*)d_in[2];  const float* bl1 = (const float*)d_in[3];
  const float* Wr1 = (const float*)d_in[4];  const float* br1 = (const float*)d_in[5];
  const float* att1= (const float*)d_in[6];  const float* bias1=(const float*)d_in[7];
  const float* Wl2 = (const float*)d_in[8];  const float* bl2 = (const float*)d_in[9];
  const float* Wr2 = (const float*)d_in[10]; const float* br2 = (const float*)d_in[11];
  const float* att2= (const float*)d_in[12]; const float* bias2=(const float*)d_in[13];
  const float* Wres= (const float*)d_in[14]; const float* bres= (const float*)d_in[15];
  const float* Wd  = (const float*)d_in[16]; const float* bd  = (const float*)d_in[17];
  const float* Wg  = (const float*)d_in[18]; const float* bg  = (const float*)d_in[19];
  const float* Wf1 = (const float*)d_in[20]; const float* bf1 = (const float*)d_in[21];
  const float* Wf2 = (const float*)d_in[22]; const float* bf2 = (const float*)d_in[23];
  const float* Wf3 = (const float*)d_in[24]; const float* bf3 = (const float*)d_in[25];
  const int* ei    = (const int*)d_in[26];
  const int* batch = (const int*)d_in[27];
  const int* esrc = ei;
  const int* edst = ei + NE;
  float* outp = (float*)d_out;

  char* p = (char*)d_ws;
  auto carve = [&](size_t bytes) { char* r = p; p += (bytes + 255) & ~(size_t)255; return r; };
  int* bcnt     = (int*)carve((size_t)NBUK * 4);
  int* bbase    = (int*)carve((size_t)(NBUK + 1) * 4);
  int* bcur     = (int*)carve((size_t)NBUK * 4);
  int* tmpv     = (int*)carve((size_t)NE * 4);
  int* ssrc     = (int*)carve((size_t)NE * 4);
  int* offs     = (int*)carve((size_t)(NN + 1) * 4);
  unsigned short* wh = (unsigned short*)carve((size_t)5 * 2 * 8192 * 2);
  unsigned short* wl = (unsigned short*)carve((size_t)5 * 2 * 8192 * 2);
  unsigned short* ximg = (unsigned short*)carve((size_t)NBLK * 16384 * 2);  // A image
  unsigned short* xl = (unsigned short*)carve((size_t)NN * FD * 2);
  unsigned short* xr = (unsigned short*)carve((size_t)NN * FD * 2);
  float* res    = (float*)carve((size_t)NN * FD * 4);
  float* h1     = (float*)carve((size_t)NN * FD * 4);
  float* pooled = (float*)carve((size_t)NB * FD * 4);
  float* h2 = res;                 // res dead after first GAT; alias
  unsigned short* himg = ximg;     // ximg dead after layer-1 linears; alias

  dim3 b256(256);
  hipLaunchKernelGGL(k_init, dim3((NB * FD + 255) / 256), b256, 0, stream, bcnt, pooled);
  hipLaunchKernelGGL(k_wprep, dim3(40), b256, 0, stream, Wl1, Wr1, Wres, Wl2, Wr2, wh, wl);
  hipLaunchKernelGGL(k_xprep, dim3((NN * 16 + 255) / 256), b256, 0, stream, x, ximg);
  hipLaunchKernelGGL(k_bhist, dim3(256), b256, 0, stream, edst, bcnt);
  hipLaunchKernelGGL(k_bscan, dim3(1), b256, 0, stream, bcnt, bbase, bcur);
  hipLaunchKernelGGL(k_bscatter, dim3(256), b256, 0, stream, esrc, edst, bcur, tmpv);
  hipLaunchKernelGGL(k_bcsr, dim3(NBUK), b256, 0, stream, tmpv, bbase, offs, ssrc);

  // layer 1: {xl, xr, res} — blockIdx.y = matrix
  hipLaunchKernelGGL(k_linm2, dim3(NBLK, 3), dim3(512), 0, stream,
                     ximg, wh, wl, 0, bl1, br1, bres, xl, xr, res, NN);
  hipLaunchKernelGGL(k_gat, dim3((NN + 7) / 8), b256, 0, stream,
                     xl, xr, offs, ssrc, att1, bias1, res, h1, himg);
  // layer 2: {xl, xr}
  hipLaunchKernelGGL(k_linm2, dim3(NBLK, 2), dim3(512), 0, stream,
                     himg, wh, wl, 3, bl2, br2, (const float*)nullptr, xl, xr, (float*)nullptr, NN);
  hipLaunchKernelGGL(k_gat, dim3((NN + 7) / 8), b256, 0, stream,
                     xl, xr, offs, ssrc, att2, bias2, h1, h2, (unsigned short*)nullptr);
  hipLaunchKernelGGL(k_pool, dim3((NN + 127) / 128), b256, 0, stream, h2, batch, pooled);
  hipLaunchKernelGGL(k_mlp, dim3(NB), dim3(128), 0, stream, pooled, batch, domain,
                     Wg, bg, Wd, bd, Wf1, bf1, Wf2, bf2, Wf3, bf3, outp);
}

// Round 10
// 204.583 us; speedup vs baseline: 1.7635x; 1.2755x over previous
//
#include <hip/hip_runtime.h>
#include <math.h>

#define NN 50000
#define NE 800000
#define FD 128      // IN == HC == 128
#define NB 64
#define NBUK 196            // ceil(NN/256) buckets of 256 dst nodes
#define CHK 3125            // NE / 256 blocks
#define CAP 6144            // LDS staging capacity per bucket (mean 4082, std ~64)
#define NBLK 782            // ceil(NN/64) 64-row tiles for the linears

typedef __attribute__((ext_vector_type(8))) short short8v;
typedef __attribute__((ext_vector_type(4))) float f32x4;

// ---------------- bf16 helpers ----------------
__device__ __forceinline__ unsigned short f2bf(float f) {
  unsigned u = __float_as_uint(f);
  u += 0x7fffu + ((u >> 16) & 1);          // RNE
  return (unsigned short)(u >> 16);
}
__device__ __forceinline__ float bfh2f(unsigned short h) {
  return __uint_as_float(((unsigned)h) << 16);
}
__device__ __forceinline__ float lrelu(float x) { return x > 0.f ? x : 0.2f * x; }

// himg/ximg image coords for node n, 32-lane id holding cols 4*lane..4*lane+3
__device__ __forceinline__ size_t img_base(int n, int lane) {
  int lrow = n & 63, blk = n >> 6;
  int kh = lane >> 4, s7 = (lane >> 1) & 7, off4 = (lane & 1) * 4;
  return (size_t)blk * 16384 + kh * 8192 + lrow * 64 + 8 * (s7 ^ (lrow & 7)) + off4;
}

// ================= K1: [wprep | bhist] =================
// wprep: pre-split + pre-swizzle 5 weight matrices into hi/lo images.
// bhist: bucket histogram of dst>>8.
__global__ __launch_bounds__(256) void k_prep1(const float* __restrict__ W0,
    const float* __restrict__ W1, const float* __restrict__ W2,
    const float* __restrict__ W3, const float* __restrict__ W4,
    unsigned short* __restrict__ wh, unsigned short* __restrict__ wl,
    const int* __restrict__ dst, int* __restrict__ bcnt) {
  __shared__ int bh[NBUK];
  int bx = blockIdx.x;
  if (bx < 40) {
    int id = bx * 256 + threadIdx.x;
    if (id >= 5 * 2048) return;
    int w = id >> 11, rem = id & 2047;
    int row = rem >> 4, slot = rem & 15;
    const float* Wp = (w == 0) ? W0 : (w == 1) ? W1 : (w == 2) ? W2 : (w == 3) ? W3 : W4;
    const float* sp = &Wp[row * 128 + slot * 8];
    int kh = slot >> 3, s7 = slot & 7;
    int d = ((w * 2 + kh) * 8192) + row * 64 + 8 * (s7 ^ (row & 7));
    short8v hi, lo;
    #pragma unroll
    for (int j = 0; j < 8; ++j) {
      float f = sp[j];
      unsigned short h = f2bf(f);
      hi[j] = (short)h;
      lo[j] = (short)f2bf(f - bfh2f(h));
    }
    *(short8v*)&wh[d] = hi;
    *(short8v*)&wl[d] = lo;
  } else {
    int b = bx - 40;                      // 0..255
    int t = threadIdx.x;
    for (int i = t; i < NBUK; i += 256) bh[i] = 0;
    __syncthreads();
    int e0 = b * CHK, e1 = e0 + CHK;
    if (e1 > NE) e1 = NE;
    for (int e = e0 + t; e < e1; e += 256) atomicAdd(&bh[dst[e] >> 8], 1);
    __syncthreads();
    for (int i = t; i < NBUK; i += 256) if (bh[i]) atomicAdd(&bcnt[i], bh[i]);
  }
}

// ================= K2: scan of 196 bucket counts =================
__global__ __launch_bounds__(256) void k_bscan(const int* __restrict__ bcnt,
                                               int* __restrict__ bbase,
                                               int* __restrict__ bcur) {
  __shared__ int wsum[4];
  int t = threadIdx.x;
  int v = (t < NBUK) ? bcnt[t] : 0;
  int lane = t & 63, wv = t >> 6;
  int s = v;
  #pragma unroll
  for (int off = 1; off < 64; off <<= 1) {
    int y = __shfl_up(s, off, 64);
    if (lane >= off) s += y;
  }
  if (lane == 63) wsum[wv] = s;
  __syncthreads();
  if (t == 0) {
    int r = 0;
    #pragma unroll
    for (int i = 0; i < 4; ++i) { int x = wsum[i]; wsum[i] = r; r += x; }
  }
  __syncthreads();
  int excl = s - v + wsum[wv];
  if (t < NBUK) { bbase[t] = excl; bcur[t] = excl; }
  if (t == NBUK - 1) bbase[NBUK] = excl + v;
}

// ================= K3: [xprep | bscatter] =================
// xprep: pack x into swizzled hi/lo A-image. bscatter: bucket-ordered edge list.
__global__ __launch_bounds__(256) void k_prep2(const float* __restrict__ x,
    unsigned short* __restrict__ ximg,
    const int* __restrict__ src, const int* __restrict__ dst,
    int* __restrict__ bcur, int* __restrict__ tmpv) {
  __shared__ int bh[NBUK];
  __shared__ int bb[NBUK];
  __shared__ int brun[NBUK];
  int bx = blockIdx.x;
  if (bx < 3125) {
    int id = bx * 256 + threadIdx.x;   // < NN*16 = 800000 exactly
    int row = id >> 4, slot = id & 15;
    const float* sp = &x[(size_t)row * 128 + slot * 8];
    int blk = row >> 6, lrow = row & 63, kh = slot >> 3, s7 = slot & 7;
    size_t hoff = (size_t)blk * 16384 + kh * 8192 + lrow * 64 + 8 * (s7 ^ (lrow & 7));
    short8v hi, lo;
    #pragma unroll
    for (int j = 0; j < 8; ++j) {
      float f = sp[j];
      unsigned short h = f2bf(f);
      hi[j] = (short)h;
      lo[j] = (short)f2bf(f - bfh2f(h));
    }
    *(short8v*)&ximg[hoff] = hi;
    *(short8v*)&ximg[hoff + 4096] = lo;
  } else {
    int b = bx - 3125;                 // 0..255
    int t = threadIdx.x;
    int e0 = b * CHK, e1 = e0 + CHK;
    if (e1 > NE) e1 = NE;
    for (int i = t; i < NBUK; i += 256) { bh[i] = 0; brun[i] = 0; }
    __syncthreads();
    for (int e = e0 + t; e < e1; e += 256) atomicAdd(&bh[dst[e] >> 8], 1);
    __syncthreads();
    for (int i = t; i < NBUK; i += 256)
      bb[i] = bh[i] ? atomicAdd(&bcur[i], bh[i]) : 0;
    __syncthreads();
    for (int e = e0 + t; e < e1; e += 256) {
      int d = dst[e];
      int bk = d >> 8;
      int p = bb[bk] + atomicAdd(&brun[bk], 1);
      tmpv[p] = (src[e] << 8) | (d & 255);
    }
  }
}

// ---------------- MFMA linear body: LDS-staged from prepacked images ----------------
// 512 threads (8 waves, 2x4), wave tile 32x32, K in two 64-halves. All staging is
// pure 16B copies. 3 MFMA per K-slice (hi*hi+hi*lo+lo*hi), fp32 acc. 48 KB smem.
__device__ __forceinline__ void linm2_body(
    const unsigned short* __restrict__ aimg,
    const unsigned short* __restrict__ wh_img, const unsigned short* __restrict__ wl_img,
    int wimg, const float* __restrict__ bias,
    unsigned short* __restrict__ out_bf, float* __restrict__ out_f,
    int blk, char* smem) {
  unsigned short* s_a  = (unsigned short*)smem;          // 16 KB (hi 0..4095, lo 4096..8191)
  unsigned short* s_wh = s_a + 8192;                     // 16 KB
  unsigned short* s_wl = s_wh + 8192;                    // 16 KB
  const int tid = threadIdx.x;
  const int lane = tid & 63;
  const int wv = tid >> 6;
  const int m0 = (wv >> 2) * 32;
  const int n0 = (wv & 3) * 32;
  const int rbase = blk * 64;
  const int g = lane >> 4, lr = lane & 15;

  f32x4 acc[2][2];
  #pragma unroll
  for (int mt = 0; mt < 2; ++mt)
    #pragma unroll
    for (int nt = 0; nt < 2; ++nt)
      acc[mt][nt] = (f32x4){0.f, 0.f, 0.f, 0.f};

  for (int kh = 0; kh < 2; ++kh) {
    if (kh) __syncthreads();
    {
      const short8v* asrc = (const short8v*)(aimg + (size_t)blk * 16384 + kh * 8192);
      short8v* adst = (short8v*)s_a;
      adst[tid] = asrc[tid];
      adst[512 + tid] = asrc[512 + tid];
    }
    {
      const short8v* whs = (const short8v*)(wh_img + (size_t)(wimg * 2 + kh) * 8192);
      const short8v* wls = (const short8v*)(wl_img + (size_t)(wimg * 2 + kh) * 8192);
      short8v* whd = (short8v*)s_wh;
      short8v* wld = (short8v*)s_wl;
      whd[tid] = whs[tid]; whd[512 + tid] = whs[512 + tid];
      wld[tid] = wls[tid]; wld[512 + tid] = wls[512 + tid];
    }
    __syncthreads();
    #pragma unroll
    for (int ks = 0; ks < 2; ++ks) {
      const int slot = ks * 4 + g;
      short8v ah[2], al[2];
      #pragma unroll
      for (int mt = 0; mt < 2; ++mt) {
        int row = m0 + mt * 16 + lr;
        int idx = row * 64 + 8 * (slot ^ (row & 7));
        ah[mt] = *(const short8v*)&s_a[idx];
        al[mt] = *(const short8v*)&s_a[idx + 4096];
      }
      #pragma unroll
      for (int nt = 0; nt < 2; ++nt) {
        int row2 = n0 + nt * 16 + lr;
        int idx2 = row2 * 64 + 8 * (slot ^ (row2 & 7));
        short8v bh = *(const short8v*)&s_wh[idx2];
        short8v bl = *(const short8v*)&s_wl[idx2];
        #pragma unroll
        for (int mt = 0; mt < 2; ++mt) {
          acc[mt][nt] = __builtin_amdgcn_mfma_f32_16x16x32_bf16(ah[mt], bh, acc[mt][nt], 0, 0, 0);
          acc[mt][nt] = __builtin_amdgcn_mfma_f32_16x16x32_bf16(ah[mt], bl, acc[mt][nt], 0, 0, 0);
          acc[mt][nt] = __builtin_amdgcn_mfma_f32_16x16x32_bf16(al[mt], bh, acc[mt][nt], 0, 0, 0);
        }
      }
    }
  }
  #pragma unroll
  for (int nt = 0; nt < 2; ++nt) {
    float bv = bias[n0 + nt * 16 + lr];
    #pragma unroll
    for (int mt = 0; mt < 2; ++mt)
      #pragma unroll
      for (int i = 0; i < 4; ++i) {
        int r = rbase + m0 + mt * 16 + 4 * g + i;
        if (r < NN) {
          float vv = acc[mt][nt][i] + bv;
          size_t o = (size_t)r * 128 + n0 + nt * 16 + lr;
          if (out_f) out_f[o] = vv;
          else out_bf[o] = f2bf(vv);
        }
      }
  }
}

// ================= K4: [bcsr | linm2 layer-1 (3 matrices)] =================
__global__ __launch_bounds__(512, 6) void k_csrlin(
    const int* __restrict__ tmpv, const int* __restrict__ bbase,
    int* __restrict__ offs, int* __restrict__ ssrc,
    const unsigned short* __restrict__ ximg,
    const unsigned short* __restrict__ wh_img, const unsigned short* __restrict__ wl_img,
    const float* __restrict__ bl1, const float* __restrict__ br1, const float* __restrict__ bres,
    unsigned short* __restrict__ xl, unsigned short* __restrict__ xr,
    float* __restrict__ res) {
  __shared__ __align__(16) char smem[49152];
  int bx = blockIdx.x;
  if (bx < NBUK) {
    // ---- bcsr at 512 threads ----
    int* sdeg = (int*)smem;          // 256
    int* scur = sdeg + 256;          // 256
    int* wsum = scur + 256;          // 16
    int* lsrc = wsum + 16;           // CAP
    int b = bx, t = threadIdx.x;
    int es = bbase[b], ee = bbase[b + 1];
    int cnt = ee - es;
    if (t < 256) sdeg[t] = 0;
    __syncthreads();
    for (int i = t; i < cnt; i += 512) atomicAdd(&sdeg[tmpv[es + i] & 255], 1);
    __syncthreads();
    int v = 0, s = 0;
    int lane = t & 63, wv = t >> 6;
    if (t < 256) {
      v = sdeg[t];
      s = v;
      #pragma unroll
      for (int off = 1; off < 64; off <<= 1) {
        int y = __shfl_up(s, off, 64);
        if (lane >= off) s += y;
      }
      if (lane == 63) wsum[wv] = s;
    }
    __syncthreads();
    if (t == 0) {
      int r = 0;
      #pragma unroll
      for (int i = 0; i < 4; ++i) { int x2 = wsum[i]; wsum[i] = r; r += x2; }
    }
    __syncthreads();
    if (t < 256) {
      int excl = s - v + wsum[wv];
      scur[t] = excl;
      int node = b * 256 + t;
      if (node < NN) offs[node] = es + excl;
    }
    if (b == 0 && t == 0) offs[NN] = NE;
    __syncthreads();
    if (cnt <= CAP) {
      for (int i = t; i < cnt; i += 512) {
        int pkt = tmpv[es + i];
        int p = atomicAdd(&scur[pkt & 255], 1);
        lsrc[p] = pkt >> 8;
      }
      __syncthreads();
      for (int i = t; i < cnt; i += 512) ssrc[es + i] = lsrc[i];
    } else {
      for (int i = t; i < cnt; i += 512) {
        int pkt = tmpv[es + i];
        int p = atomicAdd(&scur[pkt & 255], 1);
        ssrc[es + p] = pkt >> 8;
      }
    }
  } else {
    int bf = bx - NBUK;
    int w = bf / NBLK, blk = bf % NBLK;
    const float* bias = (w == 0) ? bl1 : (w == 1) ? br1 : bres;
    unsigned short* obf = (w == 0) ? xl : (w == 1) ? xr : (unsigned short*)nullptr;
    float* of = (w == 2) ? res : (float*)nullptr;
    linm2_body(ximg, wh_img, wl_img, w, bias, obf, of, blk, smem);
  }
}

// ================= K6: linm2 layer-2 (2 matrices) =================
__global__ __launch_bounds__(512, 6) void k_lin2(
    const unsigned short* __restrict__ himg,
    const unsigned short* __restrict__ wh_img, const unsigned short* __restrict__ wl_img,
    const float* __restrict__ bl2, const float* __restrict__ br2,
    unsigned short* __restrict__ xl, unsigned short* __restrict__ xr) {
  __shared__ __align__(16) char smem[49152];
  int w = blockIdx.y;
  linm2_body(himg, wh_img, wl_img, 3 + w, (w == 0) ? bl2 : br2,
             (w == 0) ? xl : xr, (float*)nullptr, blockIdx.x, smem);
}

// ---------------- GATv2 core: bf16 gathers, no-max softmax, 4-wide MLP ----------------
__device__ __forceinline__ float4 gat_core(const unsigned short* __restrict__ xl,
    const unsigned short* __restrict__ xr, const int* __restrict__ offs,
    const int* __restrict__ ssrc, const float* __restrict__ att,
    const float* __restrict__ bias, int n, int lane) {
  float4 att4 = ((const float4*)att)[lane];
  ushort4 xu = ((const ushort4*)xr)[(size_t)n * 32 + lane];
  float4 xr4 = make_float4(bfh2f(xu.x), bfh2f(xu.y), bfh2f(xu.z), bfh2f(xu.w));
  int e0 = offs[n], e1 = offs[n + 1];
  float den = 0.f;
  float4 acc = make_float4(0.f, 0.f, 0.f, 0.f);
  int e = e0;
  for (; e + 3 < e1; e += 4) {
    ushort4 u[4];
    #pragma unroll
    for (int j = 0; j < 4; ++j) {
      int s = ssrc[e + j];
      u[j] = ((const ushort4*)xl)[(size_t)s * 32 + lane];
    }
    #pragma unroll
    for (int j = 0; j < 4; ++j) {
      float4 v = make_float4(bfh2f(u[j].x), bfh2f(u[j].y), bfh2f(u[j].z), bfh2f(u[j].w));
      float p = lrelu(v.x + xr4.x) * att4.x + lrelu(v.y + xr4.y) * att4.y +
                lrelu(v.z + xr4.z) * att4.z + lrelu(v.w + xr4.w) * att4.w;
      p += __shfl_xor(p, 1, 64); p += __shfl_xor(p, 2, 64); p += __shfl_xor(p, 4, 64);
      float w = __expf(p);
      den += w;
      acc.x += w * v.x; acc.y += w * v.y; acc.z += w * v.z; acc.w += w * v.w;
    }
  }
  for (; e < e1; ++e) {
    int s = ssrc[e];
    ushort4 u0 = ((const ushort4*)xl)[(size_t)s * 32 + lane];
    float4 v = make_float4(bfh2f(u0.x), bfh2f(u0.y), bfh2f(u0.z), bfh2f(u0.w));
    float p = lrelu(v.x + xr4.x) * att4.x + lrelu(v.y + xr4.y) * att4.y +
              lrelu(v.z + xr4.z) * att4.z + lrelu(v.w + xr4.w) * att4.w;
    p += __shfl_xor(p, 1, 64); p += __shfl_xor(p, 2, 64); p += __shfl_xor(p, 4, 64);
    float w = __expf(p);
    den += w;
    acc.x += w * v.x; acc.y += w * v.y; acc.z += w * v.z; acc.w += w * v.w;
  }
  float inv = (den > 0.f) ? 1.f / den : 0.f;
  float4 b4 = ((const float4*)bias)[lane];
  float4 o;
  o.x = fmaxf(acc.x * inv + b4.x, 0.f);
  o.y = fmaxf(acc.y * inv + b4.y, 0.f);
  o.z = fmaxf(acc.z * inv + b4.z, 0.f);
  o.w = fmaxf(acc.w * inv + b4.w, 0.f);
  return o;
}

// ================= K5: GAT layer 1 — writes ONLY the hi/lo himg image =================
__global__ __launch_bounds__(256) void k_gat1(const unsigned short* __restrict__ xl,
    const unsigned short* __restrict__ xr, const int* __restrict__ offs,
    const int* __restrict__ ssrc, const float* __restrict__ att,
    const float* __restrict__ bias, const float* __restrict__ resid,
    unsigned short* __restrict__ himg) {
  int grp = threadIdx.x >> 5;
  int lane = threadIdx.x & 31;
  int n = blockIdx.x * 8 + grp;     // NN % 8 == 0: always valid
  float4 o = gat_core(xl, xr, offs, ssrc, att, bias, n, lane);
  float4 r4 = ((const float4*)resid)[(size_t)n * 32 + lane];
  o.x += r4.x; o.y += r4.y; o.z += r4.z; o.w += r4.w;
  size_t base = img_base(n, lane);
  ushort4 hi, lo;
  hi.x = f2bf(o.x); lo.x = f2bf(o.x - bfh2f(hi.x));
  hi.y = f2bf(o.y); lo.y = f2bf(o.y - bfh2f(hi.y));
  hi.z = f2bf(o.z); lo.z = f2bf(o.z - bfh2f(hi.z));
  hi.w = f2bf(o.w); lo.w = f2bf(o.w - bfh2f(hi.w));
  *(ushort4*)&himg[base] = hi;
  *(ushort4*)&himg[base + 4096] = lo;
}

// ================= K7: GAT layer 2 + fused mean-pool accumulation =================
__global__ __launch_bounds__(256) void k_gatpool(const unsigned short* __restrict__ xl,
    const unsigned short* __restrict__ xr, const int* __restrict__ offs,
    const int* __restrict__ ssrc, const float* __restrict__ att,
    const float* __restrict__ bias, const unsigned short* __restrict__ himg,
    const int* __restrict__ batch, float* __restrict__ pooled) {
  __shared__ float sm[8][128];
  __shared__ int sbat[8];
  int grp = threadIdx.x >> 5;
  int lane = threadIdx.x & 31;
  int n = blockIdx.x * 8 + grp;
  float4 o = gat_core(xl, xr, offs, ssrc, att, bias, n, lane);
  // residual = h1 reconstructed from hi/lo image (error ~2^-17 relative)
  size_t base = img_base(n, lane);
  ushort4 rh = *(const ushort4*)&himg[base];
  ushort4 rl = *(const ushort4*)&himg[base + 4096];
  o.x += bfh2f(rh.x) + bfh2f(rl.x);
  o.y += bfh2f(rh.y) + bfh2f(rl.y);
  o.z += bfh2f(rh.z) + bfh2f(rl.z);
  o.w += bfh2f(rh.w) + bfh2f(rl.w);
  *(float4*)&sm[grp][lane * 4] = o;
  if (threadIdx.x < 8) sbat[threadIdx.x] = batch[blockIdx.x * 8 + threadIdx.x];
  __syncthreads();
  int t = threadIdx.x;
  if (t < 128) {
    float run = sm[0][t];
    int cb = sbat[0];
    #pragma unroll
    for (int g2 = 1; g2 < 8; ++g2) {
      int bb = sbat[g2];
      if (bb != cb) { atomicAdd(&pooled[cb * FD + t], run); run = 0.f; cb = bb; }
      run += sm[g2][t];
    }
    atomicAdd(&pooled[cb * FD + t], run);
  }
}

// ================= K8: MLP head =================
__global__ __launch_bounds__(128) void k_mlp(const float* __restrict__ pooled,
    const int* __restrict__ batch, const float* __restrict__ domain,
    const float* __restrict__ Wg, const float* __restrict__ bg,
    const float* __restrict__ Wd, const float* __restrict__ bd,
    const float* __restrict__ Wf1, const float* __restrict__ bf1,
    const float* __restrict__ Wf2, const float* __restrict__ bf2,
    const float* __restrict__ Wf3, const float* __restrict__ bf3,
    float* __restrict__ out) {
  __shared__ float z[192];
  __shared__ float z1[128];
  __shared__ float z2[64];
  __shared__ float pm[128];
  __shared__ int cnt;
  int b = blockIdx.x, t = threadIdx.x;
  if (t == 0) {
    int lo = 0, hi = NN;
    while (lo < hi) { int mid = (lo + hi) >> 1; if (batch[mid] < b) lo = mid + 1; else hi = mid; }
    int lb = lo; lo = 0; hi = NN;
    while (lo < hi) { int mid = (lo + hi) >> 1; if (batch[mid] < b + 1) lo = mid + 1; else hi = mid; }
    cnt = lo - lb;
  }
  __syncthreads();
  float invc = 1.f / fmaxf((float)cnt, 1.f);
  pm[t] = pooled[b * FD + t] * invc;
  __syncthreads();
  {
    float a = bg[t];
    for (int k = 0; k < 128; ++k) a += pm[k] * Wg[t * 128 + k];
    z[t] = fmaxf(a, 0.f);
  }
  if (t < 64) {
    float a = bd[t];
    for (int k = 0; k < 32; ++k) a += domain[b * 32 + k] * Wd[t * 32 + k];
    z[128 + t] = fmaxf(a, 0.f);
  }
  __syncthreads();
  {
    float a = bf1[t];
    for (int k = 0; k < 192; ++k) a += z[k] * Wf1[t * 192 + k];
    z1[t] = fmaxf(a, 0.f);
  }
  __syncthreads();
  if (t < 64) {
    float a = bf2[t];
    for (int k = 0; k < 128; ++k) a += z1[k] * Wf2[t * 128 + k];
    z2[t] = fmaxf(a, 0.f);
  }
  __syncthreads();
  if (t < 64) {
    float v = z2[t] * Wf3[t];
    for (int off = 1; off < 64; off <<= 1) v += __shfl_xor(v, off, 64);
    if (t == 0) out[b] = v + bf3[0];
  }
}

extern "C" void kernel_launch(void* const* d_in, const int* in_sizes, int n_in,
                              void* d_out, int out_size, void* d_ws, size_t ws_size,
                              hipStream_t stream) {
  const float* x      = (const float*)d_in[0];
  const float* domain = (const float*)d_in[1];
  const float* Wl1 = (const float*)d_in[2];  const float* bl1 = (const float*)d_in[3];
  const float* Wr1 = (const float*)d_in[4];  const float* br1 = (const float*)d_in[5];
  const float* att1= (const float*)d_in[6];  const float* bias1=(const float*)d_in[7];
  const float* Wl2 = (const float*)d_in[8];  const float* bl2 = (const float*)d_in[9];
  const float* Wr2 = (const float*)d_in[10]; const float* br2 = (const float*)d_in[11];
  const float* att2= (const float*)d_in[12]; const float* bias2=(const float*)d_in[13];
  const float* Wres= (const float*)d_in[14]; const float* bres= (const float*)d_in[15];
  const float* Wd  = (const float*)d_in[16]; const float* bd  = (const float*)d_in[17];
  const float* Wg  = (const float*)d_in[18]; const float* bg  = (const float*)d_in[19];
  const float* Wf1 = (const float*)d_in[20]; const float* bf1 = (const float*)d_in[21];
  const float* Wf2 = (const float*)d_in[22]; const float* bf2 = (const float*)d_in[23];
  const float* Wf3 = (const float*)d_in[24]; const float* bf3 = (const float*)d_in[25];
  const int* ei    = (const int*)d_in[26];
  const int* batch = (const int*)d_in[27];
  const int* esrc = ei;
  const int* edst = ei + NE;
  float* outp = (float*)d_out;

  char* p = (char*)d_ws;
  auto carve = [&](size_t bytes) { char* r = p; p += (bytes + 255) & ~(size_t)255; return r; };
  int* bcnt     = (int*)carve((size_t)NBUK * 4);
  int* bbase    = (int*)carve((size_t)(NBUK + 1) * 4);
  int* bcur     = (int*)carve((size_t)NBUK * 4);
  int* tmpv     = (int*)carve((size_t)NE * 4);
  int* ssrc     = (int*)carve((size_t)NE * 4);
  int* offs     = (int*)carve((size_t)(NN + 1) * 4);
  unsigned short* wh = (unsigned short*)carve((size_t)5 * 2 * 8192 * 2);
  unsigned short* wl = (unsigned short*)carve((size_t)5 * 2 * 8192 * 2);
  unsigned short* ximg = (unsigned short*)carve((size_t)NBLK * 16384 * 2);  // A image (aliased as himg)
  unsigned short* xl = (unsigned short*)carve((size_t)NN * FD * 2);
  unsigned short* xr = (unsigned short*)carve((size_t)NN * FD * 2);
  float* res    = (float*)carve((size_t)NN * FD * 4);
  float* pooled = (float*)carve((size_t)NB * FD * 4);
  unsigned short* himg = ximg;     // ximg dead after layer-1 linears; alias

  hipMemsetAsync(bcnt, 0, (size_t)NBUK * 4, stream);
  hipMemsetAsync(pooled, 0, (size_t)NB * FD * 4, stream);

  dim3 b256(256);
  // K1: [wprep(40) | bhist(256)]
  hipLaunchKernelGGL(k_prep1, dim3(40 + 256), b256, 0, stream,
                     Wl1, Wr1, Wres, Wl2, Wr2, wh, wl, edst, bcnt);
  // K2: bucket scan
  hipLaunchKernelGGL(k_bscan, dim3(1), b256, 0, stream, bcnt, bbase, bcur);
  // K3: [xprep(3125) | bscatter(256)]
  hipLaunchKernelGGL(k_prep2, dim3(3125 + 256), b256, 0, stream,
                     x, ximg, esrc, edst, bcur, tmpv);
  // K4: [bcsr(196) | linm2 layer-1 (3*NBLK)]
  hipLaunchKernelGGL(k_csrlin, dim3(NBUK + 3 * NBLK), dim3(512), 0, stream,
                     tmpv, bbase, offs, ssrc, ximg, wh, wl, bl1, br1, bres, xl, xr, res);
  // K5: GAT layer 1 -> himg only
  hipLaunchKernelGGL(k_gat1, dim3(NN / 8), b256, 0, stream,
                     xl, xr, offs, ssrc, att1, bias1, res, himg);
  // K6: linm2 layer-2 (2 matrices)
  hipLaunchKernelGGL(k_lin2, dim3(NBLK, 2), dim3(512), 0, stream,
                     himg, wh, wl, bl2, br2, xl, xr);
  // K7: GAT layer 2 + pooled accumulation
  hipLaunchKernelGGL(k_gatpool, dim3(NN / 8), b256, 0, stream,
                     xl, xr, offs, ssrc, att2, bias2, himg, batch, pooled);
  // K8: MLP head
  hipLaunchKernelGGL(k_mlp, dim3(NB), dim3(128), 0, stream, pooled, batch, domain,
                     Wg, bg, Wd, bd, Wf1, bf1, Wf2, bf2, Wf3, bf3, outp);
}

// Round 11
// 198.924 us; speedup vs baseline: 1.8136x; 1.0284x over previous
//
#include <hip/hip_runtime.h>
#include <math.h>

#define NN 50000
#define NE 800000
#define FD 128      // IN == HC == 128
#define NB 64
#define NBUK 196            // ceil(NN/256) buckets of 256 dst nodes
#define CHK 3125            // NE / 256 blocks
#define CAP 6144            // LDS staging capacity per bucket (mean 4082, std ~64)
#define NBLK 782            // ceil(NN/64) 64-row tiles for the linears

typedef __attribute__((ext_vector_type(8))) short short8v;
typedef __attribute__((ext_vector_type(4))) float f32x4;
typedef _Float16 h2 __attribute__((ext_vector_type(2)));

// ---------------- bf16 helpers ----------------
__device__ __forceinline__ unsigned short f2bf(float f) {
  unsigned u = __float_as_uint(f);
  u += 0x7fffu + ((u >> 16) & 1);          // RNE
  return (unsigned short)(u >> 16);
}
__device__ __forceinline__ float bfh2f(unsigned short h) {
  return __uint_as_float(((unsigned)h) << 16);
}

// himg/ximg image coords for node n, 32-lane id holding cols 4*lane..4*lane+3
__device__ __forceinline__ size_t img_base(int n, int lane) {
  int lrow = n & 63, blk = n >> 6;
  int kh = lane >> 4, s7 = (lane >> 1) & 7, off4 = (lane & 1) * 4;
  return (size_t)blk * 16384 + kh * 8192 + lrow * 64 + 8 * (s7 ^ (lrow & 7)) + off4;
}

// ================= K1: [wprep | bhist] =================
__global__ __launch_bounds__(256) void k_prep1(const float* __restrict__ W0,
    const float* __restrict__ W1, const float* __restrict__ W2,
    const float* __restrict__ W3, const float* __restrict__ W4,
    unsigned short* __restrict__ wh, unsigned short* __restrict__ wl,
    const int* __restrict__ dst, int* __restrict__ bcnt) {
  __shared__ int bh[NBUK];
  int bx = blockIdx.x;
  if (bx < 40) {
    int id = bx * 256 + threadIdx.x;
    if (id >= 5 * 2048) return;
    int w = id >> 11, rem = id & 2047;
    int row = rem >> 4, slot = rem & 15;
    const float* Wp = (w == 0) ? W0 : (w == 1) ? W1 : (w == 2) ? W2 : (w == 3) ? W3 : W4;
    const float* sp = &Wp[row * 128 + slot * 8];
    int kh = slot >> 3, s7 = slot & 7;
    int d = ((w * 2 + kh) * 8192) + row * 64 + 8 * (s7 ^ (row & 7));
    short8v hi, lo;
    #pragma unroll
    for (int j = 0; j < 8; ++j) {
      float f = sp[j];
      unsigned short h = f2bf(f);
      hi[j] = (short)h;
      lo[j] = (short)f2bf(f - bfh2f(h));
    }
    *(short8v*)&wh[d] = hi;
    *(short8v*)&wl[d] = lo;
  } else {
    int b = bx - 40;
    int t = threadIdx.x;
    for (int i = t; i < NBUK; i += 256) bh[i] = 0;
    __syncthreads();
    int e0 = b * CHK, e1 = e0 + CHK;
    if (e1 > NE) e1 = NE;
    for (int e = e0 + t; e < e1; e += 256) atomicAdd(&bh[dst[e] >> 8], 1);
    __syncthreads();
    for (int i = t; i < NBUK; i += 256) if (bh[i]) atomicAdd(&bcnt[i], bh[i]);
  }
}

// ================= K2: scan of 196 bucket counts =================
__global__ __launch_bounds__(256) void k_bscan(const int* __restrict__ bcnt,
                                               int* __restrict__ bbase,
                                               int* __restrict__ bcur) {
  __shared__ int wsum[4];
  int t = threadIdx.x;
  int v = (t < NBUK) ? bcnt[t] : 0;
  int lane = t & 63, wv = t >> 6;
  int s = v;
  #pragma unroll
  for (int off = 1; off < 64; off <<= 1) {
    int y = __shfl_up(s, off, 64);
    if (lane >= off) s += y;
  }
  if (lane == 63) wsum[wv] = s;
  __syncthreads();
  if (t == 0) {
    int r = 0;
    #pragma unroll
    for (int i = 0; i < 4; ++i) { int x = wsum[i]; wsum[i] = r; r += x; }
  }
  __syncthreads();
  int excl = s - v + wsum[wv];
  if (t < NBUK) { bbase[t] = excl; bcur[t] = excl; }
  if (t == NBUK - 1) bbase[NBUK] = excl + v;
}

// ================= K3: [xprep | bscatter] =================
__global__ __launch_bounds__(256) void k_prep2(const float* __restrict__ x,
    unsigned short* __restrict__ ximg,
    const int* __restrict__ src, const int* __restrict__ dst,
    int* __restrict__ bcur, int* __restrict__ tmpv) {
  __shared__ int bh[NBUK];
  __shared__ int bb[NBUK];
  __shared__ int brun[NBUK];
  int bx = blockIdx.x;
  if (bx < 3125) {
    int id = bx * 256 + threadIdx.x;   // < NN*16 = 800000 exactly
    int row = id >> 4, slot = id & 15;
    const float* sp = &x[(size_t)row * 128 + slot * 8];
    int blk = row >> 6, lrow = row & 63, kh = slot >> 3, s7 = slot & 7;
    size_t hoff = (size_t)blk * 16384 + kh * 8192 + lrow * 64 + 8 * (s7 ^ (lrow & 7));
    short8v hi, lo;
    #pragma unroll
    for (int j = 0; j < 8; ++j) {
      float f = sp[j];
      unsigned short h = f2bf(f);
      hi[j] = (short)h;
      lo[j] = (short)f2bf(f - bfh2f(h));
    }
    *(short8v*)&ximg[hoff] = hi;
    *(short8v*)&ximg[hoff + 4096] = lo;
  } else {
    int b = bx - 3125;
    int t = threadIdx.x;
    int e0 = b * CHK, e1 = e0 + CHK;
    if (e1 > NE) e1 = NE;
    for (int i = t; i < NBUK; i += 256) { bh[i] = 0; brun[i] = 0; }
    __syncthreads();
    for (int e = e0 + t; e < e1; e += 256) atomicAdd(&bh[dst[e] >> 8], 1);
    __syncthreads();
    for (int i = t; i < NBUK; i += 256)
      bb[i] = bh[i] ? atomicAdd(&bcur[i], bh[i]) : 0;
    __syncthreads();
    for (int e = e0 + t; e < e1; e += 256) {
      int d = dst[e];
      int bk = d >> 8;
      int p = bb[bk] + atomicAdd(&brun[bk], 1);
      tmpv[p] = (src[e] << 8) | (d & 255);
    }
  }
}

// ---------------- MFMA linear body: LDS-staged from prepacked images ----------------
__device__ __forceinline__ void linm2_body(
    const unsigned short* __restrict__ aimg,
    const unsigned short* __restrict__ wh_img, const unsigned short* __restrict__ wl_img,
    int wimg, const float* __restrict__ bias,
    _Float16* __restrict__ out_h, float* __restrict__ out_f,
    int blk, char* smem) {
  unsigned short* s_a  = (unsigned short*)smem;          // 16 KB (hi 0..4095, lo 4096..8191)
  unsigned short* s_wh = s_a + 8192;                     // 16 KB
  unsigned short* s_wl = s_wh + 8192;                    // 16 KB
  const int tid = threadIdx.x;
  const int lane = tid & 63;
  const int wv = tid >> 6;
  const int m0 = (wv >> 2) * 32;
  const int n0 = (wv & 3) * 32;
  const int rbase = blk * 64;
  const int g = lane >> 4, lr = lane & 15;

  f32x4 acc[2][2];
  #pragma unroll
  for (int mt = 0; mt < 2; ++mt)
    #pragma unroll
    for (int nt = 0; nt < 2; ++nt)
      acc[mt][nt] = (f32x4){0.f, 0.f, 0.f, 0.f};

  for (int kh = 0; kh < 2; ++kh) {
    if (kh) __syncthreads();
    {
      const short8v* asrc = (const short8v*)(aimg + (size_t)blk * 16384 + kh * 8192);
      short8v* adst = (short8v*)s_a;
      adst[tid] = asrc[tid];
      adst[512 + tid] = asrc[512 + tid];
    }
    {
      const short8v* whs = (const short8v*)(wh_img + (size_t)(wimg * 2 + kh) * 8192);
      const short8v* wls = (const short8v*)(wl_img + (size_t)(wimg * 2 + kh) * 8192);
      short8v* whd = (short8v*)s_wh;
      short8v* wld = (short8v*)s_wl;
      whd[tid] = whs[tid]; whd[512 + tid] = whs[512 + tid];
      wld[tid] = wls[tid]; wld[512 + tid] = wls[512 + tid];
    }
    __syncthreads();
    #pragma unroll
    for (int ks = 0; ks < 2; ++ks) {
      const int slot = ks * 4 + g;
      short8v ah[2], al[2];
      #pragma unroll
      for (int mt = 0; mt < 2; ++mt) {
        int row = m0 + mt * 16 + lr;
        int idx = row * 64 + 8 * (slot ^ (row & 7));
        ah[mt] = *(const short8v*)&s_a[idx];
        al[mt] = *(const short8v*)&s_a[idx + 4096];
      }
      #pragma unroll
      for (int nt = 0; nt < 2; ++nt) {
        int row2 = n0 + nt * 16 + lr;
        int idx2 = row2 * 64 + 8 * (slot ^ (row2 & 7));
        short8v bh = *(const short8v*)&s_wh[idx2];
        short8v bl = *(const short8v*)&s_wl[idx2];
        #pragma unroll
        for (int mt = 0; mt < 2; ++mt) {
          acc[mt][nt] = __builtin_amdgcn_mfma_f32_16x16x32_bf16(ah[mt], bh, acc[mt][nt], 0, 0, 0);
          acc[mt][nt] = __builtin_amdgcn_mfma_f32_16x16x32_bf16(ah[mt], bl, acc[mt][nt], 0, 0, 0);
          acc[mt][nt] = __builtin_amdgcn_mfma_f32_16x16x32_bf16(al[mt], bh, acc[mt][nt], 0, 0, 0);
        }
      }
    }
  }
  #pragma unroll
  for (int nt = 0; nt < 2; ++nt) {
    float bv = bias[n0 + nt * 16 + lr];
    #pragma unroll
    for (int mt = 0; mt < 2; ++mt)
      #pragma unroll
      for (int i = 0; i < 4; ++i) {
        int r = rbase + m0 + mt * 16 + 4 * g + i;
        if (r < NN) {
          float vv = acc[mt][nt][i] + bv;
          size_t o = (size_t)r * 128 + n0 + nt * 16 + lr;
          if (out_f) out_f[o] = vv;
          else out_h[o] = (_Float16)vv;
        }
      }
  }
}

// ================= K4: [bcsr | linm2 layer-1 (3 matrices)] =================
__global__ __launch_bounds__(512, 6) void k_csrlin(
    const int* __restrict__ tmpv, const int* __restrict__ bbase,
    int* __restrict__ offs, int* __restrict__ ssrc,
    const unsigned short* __restrict__ ximg,
    const unsigned short* __restrict__ wh_img, const unsigned short* __restrict__ wl_img,
    const float* __restrict__ bl1, const float* __restrict__ br1, const float* __restrict__ bres,
    _Float16* __restrict__ xl, _Float16* __restrict__ xr,
    float* __restrict__ res) {
  __shared__ __align__(16) char smem[49152];
  int bx = blockIdx.x;
  if (bx < NBUK) {
    int* sdeg = (int*)smem;
    int* scur = sdeg + 256;
    int* wsum = scur + 256;
    int* lsrc = wsum + 16;
    int b = bx, t = threadIdx.x;
    int es = bbase[b], ee = bbase[b + 1];
    int cnt = ee - es;
    if (t < 256) sdeg[t] = 0;
    __syncthreads();
    for (int i = t; i < cnt; i += 512) atomicAdd(&sdeg[tmpv[es + i] & 255], 1);
    __syncthreads();
    int v = 0, s = 0;
    int lane = t & 63, wv = t >> 6;
    if (t < 256) {
      v = sdeg[t];
      s = v;
      #pragma unroll
      for (int off = 1; off < 64; off <<= 1) {
        int y = __shfl_up(s, off, 64);
        if (lane >= off) s += y;
      }
      if (lane == 63) wsum[wv] = s;
    }
    __syncthreads();
    if (t == 0) {
      int r = 0;
      #pragma unroll
      for (int i = 0; i < 4; ++i) { int x2 = wsum[i]; wsum[i] = r; r += x2; }
    }
    __syncthreads();
    if (t < 256) {
      int excl = s - v + wsum[wv];
      scur[t] = excl;
      int node = b * 256 + t;
      if (node < NN) offs[node] = es + excl;
    }
    if (b == 0 && t == 0) offs[NN] = NE;
    __syncthreads();
    if (cnt <= CAP) {
      for (int i = t; i < cnt; i += 512) {
        int pkt = tmpv[es + i];
        int p = atomicAdd(&scur[pkt & 255], 1);
        lsrc[p] = pkt >> 8;
      }
      __syncthreads();
      for (int i = t; i < cnt; i += 512) ssrc[es + i] = lsrc[i];
    } else {
      for (int i = t; i < cnt; i += 512) {
        int pkt = tmpv[es + i];
        int p = atomicAdd(&scur[pkt & 255], 1);
        ssrc[es + p] = pkt >> 8;
      }
    }
  } else {
    int bf = bx - NBUK;
    int w = bf / NBLK, blk = bf % NBLK;
    const float* bias = (w == 0) ? bl1 : (w == 1) ? br1 : bres;
    _Float16* oh = (w == 0) ? xl : (w == 1) ? xr : (_Float16*)nullptr;
    float* of = (w == 2) ? res : (float*)nullptr;
    linm2_body(ximg, wh_img, wl_img, w, bias, oh, of, blk, smem);
  }
}

// ================= K6: linm2 layer-2 (2 matrices) =================
__global__ __launch_bounds__(512, 6) void k_lin2(
    const unsigned short* __restrict__ himg,
    const unsigned short* __restrict__ wh_img, const unsigned short* __restrict__ wl_img,
    const float* __restrict__ bl2, const float* __restrict__ br2,
    _Float16* __restrict__ xl, _Float16* __restrict__ xr) {
  __shared__ __align__(16) char smem[49152];
  int w = blockIdx.y;
  linm2_body(himg, wh_img, wl_img, 3 + w, (w == 0) ? bl2 : br2,
             (w == 0) ? xl : xr, (float*)nullptr, blockIdx.x, smem);
}

// ---------------- GATv2 core: fp16 packed edge math, no-max softmax ----------------
__device__ __forceinline__ float4 gat_core(const _Float16* __restrict__ xl,
    const _Float16* __restrict__ xr, const int* __restrict__ offs,
    const int* __restrict__ ssrc, const float* __restrict__ att,
    const float* __restrict__ bias, int n, int lane) {
  float4 att4 = ((const float4*)att)[lane];
  h2 att01 = {(_Float16)att4.x, (_Float16)att4.y};
  h2 att23 = {(_Float16)att4.z, (_Float16)att4.w};
  uint2 xru = ((const uint2*)xr)[(size_t)n * 32 + lane];
  h2 xr01 = __builtin_bit_cast(h2, xru.x);
  h2 xr23 = __builtin_bit_cast(h2, xru.y);
  const h2 k02 = {(_Float16)0.2f, (_Float16)0.2f};
  int e0 = offs[n], e1 = offs[n + 1];
  float den = 0.f;
  float4 acc = make_float4(0.f, 0.f, 0.f, 0.f);
  int e = e0;
  for (; e + 3 < e1; e += 4) {
    uint2 u[4];
    #pragma unroll
    for (int j = 0; j < 4; ++j) {
      int s = ssrc[e + j];
      u[j] = ((const uint2*)xl)[(size_t)s * 32 + lane];
    }
    #pragma unroll
    for (int j = 0; j < 4; ++j) {
      h2 v01 = __builtin_bit_cast(h2, u[j].x);
      h2 v23 = __builtin_bit_cast(h2, u[j].y);
      h2 t01 = v01 + xr01;
      h2 t23 = v23 + xr23;
      h2 l01 = __builtin_elementwise_max(t01, t01 * k02);
      h2 l23 = __builtin_elementwise_max(t23, t23 * k02);
      float p = __builtin_amdgcn_fdot2(l01, att01, 0.f, false);
      p = __builtin_amdgcn_fdot2(l23, att23, p, false);
      p += __shfl_xor(p, 1, 64); p += __shfl_xor(p, 2, 64); p += __shfl_xor(p, 4, 64);
      float w = __expf(p);
      den += w;
      acc.x += w * (float)v01[0];
      acc.y += w * (float)v01[1];
      acc.z += w * (float)v23[0];
      acc.w += w * (float)v23[1];
    }
  }
  for (; e < e1; ++e) {
    int s = ssrc[e];
    uint2 uu = ((const uint2*)xl)[(size_t)s * 32 + lane];
    h2 v01 = __builtin_bit_cast(h2, uu.x);
    h2 v23 = __builtin_bit_cast(h2, uu.y);
    h2 t01 = v01 + xr01;
    h2 t23 = v23 + xr23;
    h2 l01 = __builtin_elementwise_max(t01, t01 * k02);
    h2 l23 = __builtin_elementwise_max(t23, t23 * k02);
    float p = __builtin_amdgcn_fdot2(l01, att01, 0.f, false);
    p = __builtin_amdgcn_fdot2(l23, att23, p, false);
    p += __shfl_xor(p, 1, 64); p += __shfl_xor(p, 2, 64); p += __shfl_xor(p, 4, 64);
    float w = __expf(p);
    den += w;
    acc.x += w * (float)v01[0];
    acc.y += w * (float)v01[1];
    acc.z += w * (float)v23[0];
    acc.w += w * (float)v23[1];
  }
  float inv = (den > 0.f) ? 1.f / den : 0.f;
  float4 b4 = ((const float4*)bias)[lane];
  float4 o;
  o.x = fmaxf(acc.x * inv + b4.x, 0.f);
  o.y = fmaxf(acc.y * inv + b4.y, 0.f);
  o.z = fmaxf(acc.z * inv + b4.z, 0.f);
  o.w = fmaxf(acc.w * inv + b4.w, 0.f);
  return o;
}

// ================= K5: GAT layer 1 — writes ONLY the hi/lo himg image =================
__global__ __launch_bounds__(256) void k_gat1(const _Float16* __restrict__ xl,
    const _Float16* __restrict__ xr, const int* __restrict__ offs,
    const int* __restrict__ ssrc, const float* __restrict__ att,
    const float* __restrict__ bias, const float* __restrict__ resid,
    unsigned short* __restrict__ himg) {
  int grp = threadIdx.x >> 5;
  int lane = threadIdx.x & 31;
  int n = blockIdx.x * 8 + grp;     // NN % 8 == 0: always valid
  float4 o = gat_core(xl, xr, offs, ssrc, att, bias, n, lane);
  float4 r4 = ((const float4*)resid)[(size_t)n * 32 + lane];
  o.x += r4.x; o.y += r4.y; o.z += r4.z; o.w += r4.w;
  size_t base = img_base(n, lane);
  ushort4 hi, lo;
  hi.x = f2bf(o.x); lo.x = f2bf(o.x - bfh2f(hi.x));
  hi.y = f2bf(o.y); lo.y = f2bf(o.y - bfh2f(hi.y));
  hi.z = f2bf(o.z); lo.z = f2bf(o.z - bfh2f(hi.z));
  hi.w = f2bf(o.w); lo.w = f2bf(o.w - bfh2f(hi.w));
  *(ushort4*)&himg[base] = hi;
  *(ushort4*)&himg[base + 4096] = lo;
}

// ================= K7: GAT layer 2 + fused mean-pool accumulation =================
__global__ __launch_bounds__(256) void k_gatpool(const _Float16* __restrict__ xl,
    const _Float16* __restrict__ xr, const int* __restrict__ offs,
    const int* __restrict__ ssrc, const float* __restrict__ att,
    const float* __restrict__ bias, const unsigned short* __restrict__ himg,
    const int* __restrict__ batch, float* __restrict__ pooled) {
  __shared__ float sm[8][128];
  __shared__ int sbat[8];
  int grp = threadIdx.x >> 5;
  int lane = threadIdx.x & 31;
  int n = blockIdx.x * 8 + grp;
  float4 o = gat_core(xl, xr, offs, ssrc, att, bias, n, lane);
  size_t base = img_base(n, lane);
  ushort4 rh = *(const ushort4*)&himg[base];
  ushort4 rl = *(const ushort4*)&himg[base + 4096];
  o.x += bfh2f(rh.x) + bfh2f(rl.x);
  o.y += bfh2f(rh.y) + bfh2f(rl.y);
  o.z += bfh2f(rh.z) + bfh2f(rl.z);
  o.w += bfh2f(rh.w) + bfh2f(rl.w);
  *(float4*)&sm[grp][lane * 4] = o;
  if (threadIdx.x < 8) sbat[threadIdx.x] = batch[blockIdx.x * 8 + threadIdx.x];
  __syncthreads();
  int t = threadIdx.x;
  if (t < 128) {
    float run = sm[0][t];
    int cb = sbat[0];
    #pragma unroll
    for (int g2 = 1; g2 < 8; ++g2) {
      int bb = sbat[g2];
      if (bb != cb) { atomicAdd(&pooled[cb * FD + t], run); run = 0.f; cb = bb; }
      run += sm[g2][t];
    }
    atomicAdd(&pooled[cb * FD + t], run);
  }
}

// ================= K8: MLP head =================
__global__ __launch_bounds__(128) void k_mlp(const float* __restrict__ pooled,
    const int* __restrict__ batch, const float* __restrict__ domain,
    const float* __restrict__ Wg, const float* __restrict__ bg,
    const float* __restrict__ Wd, const float* __restrict__ bd,
    const float* __restrict__ Wf1, const float* __restrict__ bf1,
    const float* __restrict__ Wf2, const float* __restrict__ bf2,
    const float* __restrict__ Wf3, const float* __restrict__ bf3,
    float* __restrict__ out) {
  __shared__ float z[192];
  __shared__ float z1[128];
  __shared__ float z2[64];
  __shared__ float pm[128];
  __shared__ int cnt;
  int b = blockIdx.x, t = threadIdx.x;
  if (t == 0) {
    int lo = 0, hi = NN;
    while (lo < hi) { int mid = (lo + hi) >> 1; if (batch[mid] < b) lo = mid + 1; else hi = mid; }
    int lb = lo; lo = 0; hi = NN;
    while (lo < hi) { int mid = (lo + hi) >> 1; if (batch[mid] < b + 1) lo = mid + 1; else hi = mid; }
    cnt = lo - lb;
  }
  __syncthreads();
  float invc = 1.f / fmaxf((float)cnt, 1.f);
  pm[t] = pooled[b * FD + t] * invc;
  __syncthreads();
  {
    float a = bg[t];
    for (int k = 0; k < 128; ++k) a += pm[k] * Wg[t * 128 + k];
    z[t] = fmaxf(a, 0.f);
  }
  if (t < 64) {
    float a = bd[t];
    for (int k = 0; k < 32; ++k) a += domain[b * 32 + k] * Wd[t * 32 + k];
    z[128 + t] = fmaxf(a, 0.f);
  }
  __syncthreads();
  {
    float a = bf1[t];
    for (int k = 0; k < 192; ++k) a += z[k] * Wf1[t * 192 + k];
    z1[t] = fmaxf(a, 0.f);
  }
  __syncthreads();
  if (t < 64) {
    float a = bf2[t];
    for (int k = 0; k < 128; ++k) a += z1[k] * Wf2[t * 128 + k];
    z2[t] = fmaxf(a, 0.f);
  }
  __syncthreads();
  if (t < 64) {
    float v = z2[t] * Wf3[t];
    for (int off = 1; off < 64; off <<= 1) v += __shfl_xor(v, off, 64);
    if (t == 0) out[b] = v + bf3[0];
  }
}

extern "C" void kernel_launch(void* const* d_in, const int* in_sizes, int n_in,
                              void* d_out, int out_size, void* d_ws, size_t ws_size,
                              hipStream_t stream) {
  const float* x      = (const float*)d_in[0];
  const float* domain = (const float*)d_in[1];
  const float* Wl1 = (const float*)d_in[2];  const float* bl1 = (const float*)d_in[3];
  const float* Wr1 = (const float*)d_in[4];  const float* br1 = (const float*)d_in[5];
  const float* att1= (const float*)d_in[6];  const float* bias1=(const float*)d_in[7];
  const float* Wl2 = (const float*)d_in[8];  const float* bl2 = (const float*)d_in[9];
  const float* Wr2 = (const float*)d_in[10]; const float* br2 = (const float*)d_in[11];
  const float* att2= (const float*)d_in[12]; const float* bias2=(const float*)d_in[13];
  const float* Wres= (const float*)d_in[14]; const float* bres= (const float*)d_in[15];
  const float* Wd  = (const float*)d_in[16]; const float* bd  = (const float*)d_in[17];
  const float* Wg  = (const float*)d_in[18]; const float* bg  = (const float*)d_in[19];
  const float* Wf1 = (const float*)d_in[20]; const float* bf1 = (const float*)d_in[21];
  const float* Wf2 = (const float*)d_in[22]; const float* bf2 = (const float*)d_in[23];
  const float* Wf3 = (const float*)d_in[24]; const float* bf3 = (const float*)d_in[25];
  const int* ei    = (const int*)d_in[26];
  const int* batch = (const int*)d_in[27];
  const int* esrc = ei;
  const int* edst = ei + NE;
  float* outp = (float*)d_out;

  char* p = (char*)d_ws;
  auto carve = [&](size_t bytes) { char* r = p; p += (bytes + 255) & ~(size_t)255; return r; };
  int* bcnt     = (int*)carve((size_t)NBUK * 4);
  int* bbase    = (int*)carve((size_t)(NBUK + 1) * 4);
  int* bcur     = (int*)carve((size_t)NBUK * 4);
  int* tmpv     = (int*)carve((size_t)NE * 4);
  int* ssrc     = (int*)carve((size_t)NE * 4);
  int* offs     = (int*)carve((size_t)(NN + 1) * 4);
  unsigned short* wh = (unsigned short*)carve((size_t)5 * 2 * 8192 * 2);
  unsigned short* wl = (unsigned short*)carve((size_t)5 * 2 * 8192 * 2);
  unsigned short* ximg = (unsigned short*)carve((size_t)NBLK * 16384 * 2);  // A image (aliased as himg)
  _Float16* xl  = (_Float16*)carve((size_t)NN * FD * 2);
  _Float16* xr  = (_Float16*)carve((size_t)NN * FD * 2);
  float* res    = (float*)carve((size_t)NN * FD * 4);
  float* pooled = (float*)carve((size_t)NB * FD * 4);
  unsigned short* himg = ximg;     // ximg dead after layer-1 linears; alias

  hipMemsetAsync(bcnt, 0, (size_t)NBUK * 4, stream);
  hipMemsetAsync(pooled, 0, (size_t)NB * FD * 4, stream);

  dim3 b256(256);
  hipLaunchKernelGGL(k_prep1, dim3(40 + 256), b256, 0, stream,
                     Wl1, Wr1, Wres, Wl2, Wr2, wh, wl, edst, bcnt);
  hipLaunchKernelGGL(k_bscan, dim3(1), b256, 0, stream, bcnt, bbase, bcur);
  hipLaunchKernelGGL(k_prep2, dim3(3125 + 256), b256, 0, stream,
                     x, ximg, esrc, edst, bcur, tmpv);
  hipLaunchKernelGGL(k_csrlin, dim3(NBUK + 3 * NBLK), dim3(512), 0, stream,
                     tmpv, bbase, offs, ssrc, ximg, wh, wl, bl1, br1, bres, xl, xr, res);
  hipLaunchKernelGGL(k_gat1, dim3(NN / 8), b256, 0, stream,
                     xl, xr, offs, ssrc, att1, bias1, res, himg);
  hipLaunchKernelGGL(k_lin2, dim3(NBLK, 2), dim3(512), 0, stream,
                     himg, wh, wl, bl2, br2, xl, xr);
  hipLaunchKernelGGL(k_gatpool, dim3(NN / 8), b256, 0, stream,
                     xl, xr, offs, ssrc, att2, bias2, himg, batch, pooled);
  hipLaunchKernelGGL(k_mlp, dim3(NB), dim3(128), 0, stream, pooled, batch, domain,
                     Wg, bg, Wd, bd, Wf1, bf1, Wf2, bf2, Wf3, bf3, outp);
}

// Round 12
// 185.464 us; speedup vs baseline: 1.9452x; 1.0726x over previous
//
#include <hip/hip_runtime.h>
#include <math.h>

#define NN 50000
#define NE 800000
#define FD 128      // IN == HC == 128
#define NB 64
#define NBUK 196            // ceil(NN/256) buckets of 256 dst nodes
#define CHK 3125            // NE / 256 blocks
#define CAP 6144            // LDS staging capacity per bucket (mean 4082, std ~64)
#define NBLK 782            // ceil(NN/64) 64-row tiles for the linears

typedef __attribute__((ext_vector_type(8))) short short8v;
typedef __attribute__((ext_vector_type(4))) float f32x4;
typedef _Float16 h2 __attribute__((ext_vector_type(2)));
typedef _Float16 h8 __attribute__((ext_vector_type(8)));

// ---------------- fp16 helpers ----------------
__device__ __forceinline__ unsigned short f2h(float f) {
  return __builtin_bit_cast(unsigned short, (_Float16)f);
}
__device__ __forceinline__ float h2f(unsigned short u) {
  return (float)__builtin_bit_cast(_Float16, u);
}

// fp16-single image coords for node n, 32-lane id holding cols 4*lane..4*lane+3
// Per 64-row blk: [kh0 8KB][kh1 8KB], per kh: row*64 + 8*(slot ^ (row&7)), slot of 8 fp16.
__device__ __forceinline__ size_t img_base(int n, int lane) {
  int lrow = n & 63, blk = n >> 6;
  int kh = lane >> 4, s7 = (lane >> 1) & 7, off4 = (lane & 1) * 4;
  return (size_t)blk * 8192 + kh * 4096 + lrow * 64 + 8 * (s7 ^ (lrow & 7)) + off4;
}

// ================= K1: [wprep | bhist] =================
// wprep: W -> fp16 hi/lo pre-swizzled images. bhist: bucket histogram of dst>>8.
__global__ __launch_bounds__(256) void k_prep1(const float* __restrict__ W0,
    const float* __restrict__ W1, const float* __restrict__ W2,
    const float* __restrict__ W3, const float* __restrict__ W4,
    unsigned short* __restrict__ wh, unsigned short* __restrict__ wl,
    const int* __restrict__ dst, int* __restrict__ bcnt) {
  __shared__ int bh[NBUK];
  int bx = blockIdx.x;
  if (bx < 40) {
    int id = bx * 256 + threadIdx.x;
    if (id >= 5 * 2048) return;
    int w = id >> 11, rem = id & 2047;
    int row = rem >> 4, slot = rem & 15;
    const float* Wp = (w == 0) ? W0 : (w == 1) ? W1 : (w == 2) ? W2 : (w == 3) ? W3 : W4;
    const float* sp = &Wp[row * 128 + slot * 8];
    int kh = slot >> 3, s7 = slot & 7;
    int d = ((w * 2 + kh) * 8192) + row * 64 + 8 * (s7 ^ (row & 7));
    short8v hi, lo;
    #pragma unroll
    for (int j = 0; j < 8; ++j) {
      float f = sp[j];
      _Float16 hv = (_Float16)f;
      _Float16 lv = (_Float16)(f - (float)hv);
      hi[j] = (short)__builtin_bit_cast(unsigned short, hv);
      lo[j] = (short)__builtin_bit_cast(unsigned short, lv);
    }
    *(short8v*)&wh[d] = hi;
    *(short8v*)&wl[d] = lo;
  } else {
    int b = bx - 40;
    int t = threadIdx.x;
    for (int i = t; i < NBUK; i += 256) bh[i] = 0;
    __syncthreads();
    int e0 = b * CHK, e1 = e0 + CHK;
    if (e1 > NE) e1 = NE;
    for (int e = e0 + t; e < e1; e += 256) atomicAdd(&bh[dst[e] >> 8], 1);
    __syncthreads();
    for (int i = t; i < NBUK; i += 256) if (bh[i]) atomicAdd(&bcnt[i], bh[i]);
  }
}

// ================= K2: scan of 196 bucket counts =================
__global__ __launch_bounds__(256) void k_bscan(const int* __restrict__ bcnt,
                                               int* __restrict__ bbase,
                                               int* __restrict__ bcur) {
  __shared__ int wsum[4];
  int t = threadIdx.x;
  int v = (t < NBUK) ? bcnt[t] : 0;
  int lane = t & 63, wv = t >> 6;
  int s = v;
  #pragma unroll
  for (int off = 1; off < 64; off <<= 1) {
    int y = __shfl_up(s, off, 64);
    if (lane >= off) s += y;
  }
  if (lane == 63) wsum[wv] = s;
  __syncthreads();
  if (t == 0) {
    int r = 0;
    #pragma unroll
    for (int i = 0; i < 4; ++i) { int x = wsum[i]; wsum[i] = r; r += x; }
  }
  __syncthreads();
  int excl = s - v + wsum[wv];
  if (t < NBUK) { bbase[t] = excl; bcur[t] = excl; }
  if (t == NBUK - 1) bbase[NBUK] = excl + v;
}

// ================= K3: [xprep | bscatter] =================
// xprep: pack x into fp16-single swizzled A-image.
__global__ __launch_bounds__(256) void k_prep2(const float* __restrict__ x,
    unsigned short* __restrict__ ximg,
    const int* __restrict__ src, const int* __restrict__ dst,
    int* __restrict__ bcur, int* __restrict__ tmpv) {
  __shared__ int bh[NBUK];
  __shared__ int bb[NBUK];
  __shared__ int brun[NBUK];
  int bx = blockIdx.x;
  if (bx < 3125) {
    int id = bx * 256 + threadIdx.x;   // < NN*16 = 800000 exactly
    int row = id >> 4, slot = id & 15;
    const float* sp = &x[(size_t)row * 128 + slot * 8];
    int blk = row >> 6, lrow = row & 63, kh = slot >> 3, s7 = slot & 7;
    size_t hoff = (size_t)blk * 8192 + kh * 4096 + lrow * 64 + 8 * (s7 ^ (lrow & 7));
    short8v hv;
    #pragma unroll
    for (int j = 0; j < 8; ++j)
      hv[j] = (short)f2h(sp[j]);
    *(short8v*)&ximg[hoff] = hv;
  } else {
    int b = bx - 3125;
    int t = threadIdx.x;
    int e0 = b * CHK, e1 = e0 + CHK;
    if (e1 > NE) e1 = NE;
    for (int i = t; i < NBUK; i += 256) { bh[i] = 0; brun[i] = 0; }
    __syncthreads();
    for (int e = e0 + t; e < e1; e += 256) atomicAdd(&bh[dst[e] >> 8], 1);
    __syncthreads();
    for (int i = t; i < NBUK; i += 256)
      bb[i] = bh[i] ? atomicAdd(&bcur[i], bh[i]) : 0;
    __syncthreads();
    for (int e = e0 + t; e < e1; e += 256) {
      int d = dst[e];
      int bk = d >> 8;
      int p = bb[bk] + atomicAdd(&brun[bk], 1);
      tmpv[p] = (src[e] << 8) | (d & 255);
    }
  }
}

// ---------------- MFMA linear body: fp16 A single, fp16 W hi/lo, 2 MFMA/slice -------
// 512 threads (8 waves, 2x4), wave tile 32x32, K in two 64-halves. LDS 40 KB.
__device__ __forceinline__ void linm2_body(
    const unsigned short* __restrict__ aimg,
    const unsigned short* __restrict__ wh_img, const unsigned short* __restrict__ wl_img,
    int wimg, const float* __restrict__ bias,
    _Float16* __restrict__ out_h, int blk, char* smem) {
  unsigned short* s_a  = (unsigned short*)smem;          // 8 KB
  unsigned short* s_wh = s_a + 4096;                     // 16 KB
  unsigned short* s_wl = s_wh + 8192;                    // 16 KB
  const int tid = threadIdx.x;
  const int lane = tid & 63;
  const int wv = tid >> 6;
  const int m0 = (wv >> 2) * 32;
  const int n0 = (wv & 3) * 32;
  const int rbase = blk * 64;
  const int g = lane >> 4, lr = lane & 15;

  f32x4 acc[2][2];
  #pragma unroll
  for (int mt = 0; mt < 2; ++mt)
    #pragma unroll
    for (int nt = 0; nt < 2; ++nt)
      acc[mt][nt] = (f32x4){0.f, 0.f, 0.f, 0.f};

  for (int kh = 0; kh < 2; ++kh) {
    if (kh) __syncthreads();
    {
      const short8v* asrc = (const short8v*)(aimg + (size_t)blk * 8192 + kh * 4096);
      ((short8v*)s_a)[tid] = asrc[tid];                  // 512 x 16B = 8 KB
    }
    {
      const short8v* whs = (const short8v*)(wh_img + (size_t)(wimg * 2 + kh) * 8192);
      const short8v* wls = (const short8v*)(wl_img + (size_t)(wimg * 2 + kh) * 8192);
      short8v* whd = (short8v*)s_wh;
      short8v* wld = (short8v*)s_wl;
      whd[tid] = whs[tid]; whd[512 + tid] = whs[512 + tid];
      wld[tid] = wls[tid]; wld[512 + tid] = wls[512 + tid];
    }
    __syncthreads();
    #pragma unroll
    for (int ks = 0; ks < 2; ++ks) {
      const int slot = ks * 4 + g;
      h8 a[2];
      #pragma unroll
      for (int mt = 0; mt < 2; ++mt) {
        int row = m0 + mt * 16 + lr;
        int idx = row * 64 + 8 * (slot ^ (row & 7));
        a[mt] = __builtin_bit_cast(h8, *(const short8v*)&s_a[idx]);
      }
      #pragma unroll
      for (int nt = 0; nt < 2; ++nt) {
        int row2 = n0 + nt * 16 + lr;
        int idx2 = row2 * 64 + 8 * (slot ^ (row2 & 7));
        h8 bh = __builtin_bit_cast(h8, *(const short8v*)&s_wh[idx2]);
        h8 bl = __builtin_bit_cast(h8, *(const short8v*)&s_wl[idx2]);
        #pragma unroll
        for (int mt = 0; mt < 2; ++mt) {
          acc[mt][nt] = __builtin_amdgcn_mfma_f32_16x16x32_f16(a[mt], bh, acc[mt][nt], 0, 0, 0);
          acc[mt][nt] = __builtin_amdgcn_mfma_f32_16x16x32_f16(a[mt], bl, acc[mt][nt], 0, 0, 0);
        }
      }
    }
  }
  #pragma unroll
  for (int nt = 0; nt < 2; ++nt) {
    float bv = bias[n0 + nt * 16 + lr];
    #pragma unroll
    for (int mt = 0; mt < 2; ++mt)
      #pragma unroll
      for (int i = 0; i < 4; ++i) {
        int r = rbase + m0 + mt * 16 + 4 * g + i;
        if (r < NN) {
          float vv = acc[mt][nt][i] + bv;
          out_h[(size_t)r * 128 + n0 + nt * 16 + lr] = (_Float16)vv;
        }
      }
  }
}

// ================= K4: [bcsr | linm2 layer-1 (3 matrices)] =================
__global__ __launch_bounds__(512, 8) void k_csrlin(
    const int* __restrict__ tmpv, const int* __restrict__ bbase,
    int* __restrict__ offs, int* __restrict__ ssrc,
    const unsigned short* __restrict__ ximg,
    const unsigned short* __restrict__ wh_img, const unsigned short* __restrict__ wl_img,
    const float* __restrict__ bl1, const float* __restrict__ br1, const float* __restrict__ bres,
    _Float16* __restrict__ xl, _Float16* __restrict__ xr,
    _Float16* __restrict__ res) {
  __shared__ __align__(16) char smem[40960];
  int bx = blockIdx.x;
  if (bx < NBUK) {
    int* sdeg = (int*)smem;
    int* scur = sdeg + 256;
    int* wsum = scur + 256;
    int* lsrc = wsum + 16;
    int b = bx, t = threadIdx.x;
    int es = bbase[b], ee = bbase[b + 1];
    int cnt = ee - es;
    if (t < 256) sdeg[t] = 0;
    __syncthreads();
    for (int i = t; i < cnt; i += 512) atomicAdd(&sdeg[tmpv[es + i] & 255], 1);
    __syncthreads();
    int v = 0, s = 0;
    int lane = t & 63, wv = t >> 6;
    if (t < 256) {
      v = sdeg[t];
      s = v;
      #pragma unroll
      for (int off = 1; off < 64; off <<= 1) {
        int y = __shfl_up(s, off, 64);
        if (lane >= off) s += y;
      }
      if (lane == 63) wsum[wv] = s;
    }
    __syncthreads();
    if (t == 0) {
      int r = 0;
      #pragma unroll
      for (int i = 0; i < 4; ++i) { int x2 = wsum[i]; wsum[i] = r; r += x2; }
    }
    __syncthreads();
    if (t < 256) {
      int excl = s - v + wsum[wv];
      scur[t] = excl;
      int node = b * 256 + t;
      if (node < NN) offs[node] = es + excl;
    }
    if (b == 0 && t == 0) offs[NN] = NE;
    __syncthreads();
    if (cnt <= CAP) {
      for (int i = t; i < cnt; i += 512) {
        int pkt = tmpv[es + i];
        int p = atomicAdd(&scur[pkt & 255], 1);
        lsrc[p] = pkt >> 8;
      }
      __syncthreads();
      for (int i = t; i < cnt; i += 512) ssrc[es + i] = lsrc[i];
    } else {
      for (int i = t; i < cnt; i += 512) {
        int pkt = tmpv[es + i];
        int p = atomicAdd(&scur[pkt & 255], 1);
        ssrc[es + p] = pkt >> 8;
      }
    }
  } else {
    int bf = bx - NBUK;
    int w = bf / NBLK, blk = bf % NBLK;
    const float* bias = (w == 0) ? bl1 : (w == 1) ? br1 : bres;
    _Float16* oh = (w == 0) ? xl : (w == 1) ? xr : res;
    linm2_body(ximg, wh_img, wl_img, w, bias, oh, blk, smem);
  }
}

// ================= K6: linm2 layer-2 (2 matrices) =================
__global__ __launch_bounds__(512, 8) void k_lin2(
    const unsigned short* __restrict__ himg,
    const unsigned short* __restrict__ wh_img, const unsigned short* __restrict__ wl_img,
    const float* __restrict__ bl2, const float* __restrict__ br2,
    _Float16* __restrict__ xl, _Float16* __restrict__ xr) {
  __shared__ __align__(16) char smem[40960];
  int w = blockIdx.y;
  linm2_body(himg, wh_img, wl_img, 3 + w, (w == 0) ? bl2 : br2,
             (w == 0) ? xl : xr, blockIdx.x, smem);
}

// ---------------- GATv2 core: fp16 packed edge math, no-max softmax ----------------
__device__ __forceinline__ float4 gat_core(const _Float16* __restrict__ xl,
    const _Float16* __restrict__ xr, const int* __restrict__ offs,
    const int* __restrict__ ssrc, const float* __restrict__ att,
    const float* __restrict__ bias, int n, int lane) {
  float4 att4 = ((const float4*)att)[lane];
  h2 att01 = {(_Float16)att4.x, (_Float16)att4.y};
  h2 att23 = {(_Float16)att4.z, (_Float16)att4.w};
  uint2 xru = ((const uint2*)xr)[(size_t)n * 32 + lane];
  h2 xr01 = __builtin_bit_cast(h2, xru.x);
  h2 xr23 = __builtin_bit_cast(h2, xru.y);
  const h2 k02 = {(_Float16)0.2f, (_Float16)0.2f};
  int e0 = offs[n], e1 = offs[n + 1];
  float den = 0.f;
  float4 acc = make_float4(0.f, 0.f, 0.f, 0.f);
  int e = e0;
  for (; e + 3 < e1; e += 4) {
    uint2 u[4];
    #pragma unroll
    for (int j = 0; j < 4; ++j) {
      int s = ssrc[e + j];
      u[j] = ((const uint2*)xl)[(size_t)s * 32 + lane];
    }
    #pragma unroll
    for (int j = 0; j < 4; ++j) {
      h2 v01 = __builtin_bit_cast(h2, u[j].x);
      h2 v23 = __builtin_bit_cast(h2, u[j].y);
      h2 t01 = v01 + xr01;
      h2 t23 = v23 + xr23;
      h2 l01 = __builtin_elementwise_max(t01, t01 * k02);
      h2 l23 = __builtin_elementwise_max(t23, t23 * k02);
      float p = __builtin_amdgcn_fdot2(l01, att01, 0.f, false);
      p = __builtin_amdgcn_fdot2(l23, att23, p, false);
      p += __shfl_xor(p, 1, 64); p += __shfl_xor(p, 2, 64); p += __shfl_xor(p, 4, 64);
      float w = __expf(p);
      den += w;
      acc.x += w * (float)v01[0];
      acc.y += w * (float)v01[1];
      acc.z += w * (float)v23[0];
      acc.w += w * (float)v23[1];
    }
  }
  for (; e < e1; ++e) {
    int s = ssrc[e];
    uint2 uu = ((const uint2*)xl)[(size_t)s * 32 + lane];
    h2 v01 = __builtin_bit_cast(h2, uu.x);
    h2 v23 = __builtin_bit_cast(h2, uu.y);
    h2 t01 = v01 + xr01;
    h2 t23 = v23 + xr23;
    h2 l01 = __builtin_elementwise_max(t01, t01 * k02);
    h2 l23 = __builtin_elementwise_max(t23, t23 * k02);
    float p = __builtin_amdgcn_fdot2(l01, att01, 0.f, false);
    p = __builtin_amdgcn_fdot2(l23, att23, p, false);
    p += __shfl_xor(p, 1, 64); p += __shfl_xor(p, 2, 64); p += __shfl_xor(p, 4, 64);
    float w = __expf(p);
    den += w;
    acc.x += w * (float)v01[0];
    acc.y += w * (float)v01[1];
    acc.z += w * (float)v23[0];
    acc.w += w * (float)v23[1];
  }
  float inv = (den > 0.f) ? 1.f / den : 0.f;
  float4 b4 = ((const float4*)bias)[lane];
  float4 o;
  o.x = fmaxf(acc.x * inv + b4.x, 0.f);
  o.y = fmaxf(acc.y * inv + b4.y, 0.f);
  o.z = fmaxf(acc.z * inv + b4.z, 0.f);
  o.w = fmaxf(acc.w * inv + b4.w, 0.f);
  return o;
}

// ================= K5: GAT layer 1 — writes ONLY the fp16 himg image =================
__global__ __launch_bounds__(256) void k_gat1(const _Float16* __restrict__ xl,
    const _Float16* __restrict__ xr, const int* __restrict__ offs,
    const int* __restrict__ ssrc, const float* __restrict__ att,
    const float* __restrict__ bias, const _Float16* __restrict__ resid,
    unsigned short* __restrict__ himg) {
  int grp = threadIdx.x >> 5;
  int lane = threadIdx.x & 31;
  int n = blockIdx.x * 8 + grp;     // NN % 8 == 0: always valid
  float4 o = gat_core(xl, xr, offs, ssrc, att, bias, n, lane);
  uint2 ru = ((const uint2*)resid)[(size_t)n * 32 + lane];
  h2 r01 = __builtin_bit_cast(h2, ru.x);
  h2 r23 = __builtin_bit_cast(h2, ru.y);
  o.x += (float)r01[0]; o.y += (float)r01[1];
  o.z += (float)r23[0]; o.w += (float)r23[1];
  size_t base = img_base(n, lane);
  ushort4 hv;
  hv.x = f2h(o.x); hv.y = f2h(o.y); hv.z = f2h(o.z); hv.w = f2h(o.w);
  *(ushort4*)&himg[base] = hv;
}

// ================= K7: GAT layer 2 + fused mean-pool accumulation =================
__global__ __launch_bounds__(256) void k_gatpool(const _Float16* __restrict__ xl,
    const _Float16* __restrict__ xr, const int* __restrict__ offs,
    const int* __restrict__ ssrc, const float* __restrict__ att,
    const float* __restrict__ bias, const unsigned short* __restrict__ himg,
    const int* __restrict__ batch, float* __restrict__ pooled) {
  __shared__ float sm[8][128];
  __shared__ int sbat[8];
  int grp = threadIdx.x >> 5;
  int lane = threadIdx.x & 31;
  int n = blockIdx.x * 8 + grp;
  float4 o = gat_core(xl, xr, offs, ssrc, att, bias, n, lane);
  size_t base = img_base(n, lane);
  ushort4 rh = *(const ushort4*)&himg[base];
  o.x += h2f(rh.x); o.y += h2f(rh.y); o.z += h2f(rh.z); o.w += h2f(rh.w);
  *(float4*)&sm[grp][lane * 4] = o;
  if (threadIdx.x < 8) sbat[threadIdx.x] = batch[blockIdx.x * 8 + threadIdx.x];
  __syncthreads();
  int t = threadIdx.x;
  if (t < 128) {
    float run = sm[0][t];
    int cb = sbat[0];
    #pragma unroll
    for (int g2 = 1; g2 < 8; ++g2) {
      int bb = sbat[g2];
      if (bb != cb) { atomicAdd(&pooled[cb * FD + t], run); run = 0.f; cb = bb; }
      run += sm[g2][t];
    }
    atomicAdd(&pooled[cb * FD + t], run);
  }
}

// ================= K8: MLP head =================
__global__ __launch_bounds__(128) void k_mlp(const float* __restrict__ pooled,
    const int* __restrict__ batch, const float* __restrict__ domain,
    const float* __restrict__ Wg, const float* __restrict__ bg,
    const float* __restrict__ Wd, const float* __restrict__ bd,
    const float* __restrict__ Wf1, const float* __restrict__ bf1,
    const float* __restrict__ Wf2, const float* __restrict__ bf2,
    const float* __restrict__ Wf3, const float* __restrict__ bf3,
    float* __restrict__ out) {
  __shared__ float z[192];
  __shared__ float z1[128];
  __shared__ float z2[64];
  __shared__ float pm[128];
  __shared__ int cnt;
  int b = blockIdx.x, t = threadIdx.x;
  if (t == 0) {
    int lo = 0, hi = NN;
    while (lo < hi) { int mid = (lo + hi) >> 1; if (batch[mid] < b) lo = mid + 1; else hi = mid; }
    int lb = lo; lo = 0; hi = NN;
    while (lo < hi) { int mid = (lo + hi) >> 1; if (batch[mid] < b + 1) lo = mid + 1; else hi = mid; }
    cnt = lo - lb;
  }
  __syncthreads();
  float invc = 1.f / fmaxf((float)cnt, 1.f);
  pm[t] = pooled[b * FD + t] * invc;
  __syncthreads();
  {
    float a = bg[t];
    for (int k = 0; k < 128; ++k) a += pm[k] * Wg[t * 128 + k];
    z[t] = fmaxf(a, 0.f);
  }
  if (t < 64) {
    float a = bd[t];
    for (int k = 0; k < 32; ++k) a += domain[b * 32 + k] * Wd[t * 32 + k];
    z[128 + t] = fmaxf(a, 0.f);
  }
  __syncthreads();
  {
    float a = bf1[t];
    for (int k = 0; k < 192; ++k) a += z[k] * Wf1[t * 192 + k];
    z1[t] = fmaxf(a, 0.f);
  }
  __syncthreads();
  if (t < 64) {
    float a = bf2[t];
    for (int k = 0; k < 128; ++k) a += z1[k] * Wf2[t * 128 + k];
    z2[t] = fmaxf(a, 0.f);
  }
  __syncthreads();
  if (t < 64) {
    float v = z2[t] * Wf3[t];
    for (int off = 1; off < 64; off <<= 1) v += __shfl_xor(v, off, 64);
    if (t == 0) out[b] = v + bf3[0];
  }
}

extern "C" void kernel_launch(void* const* d_in, const int* in_sizes, int n_in,
                              void* d_out, int out_size, void* d_ws, size_t ws_size,
                              hipStream_t stream) {
  const float* x      = (const float*)d_in[0];
  const float* domain = (const float*)d_in[1];
  const float* Wl1 = (const float*)d_in[2];  const float* bl1 = (const float*)d_in[3];
  const float* Wr1 = (const float*)d_in[4];  const float* br1 = (const float*)d_in[5];
  const float* att1= (const float*)d_in[6];  const float* bias1=(const float*)d_in[7];
  const float* Wl2 = (const float*)d_in[8];  const float* bl2 = (const float*)d_in[9];
  const float* Wr2 = (const float*)d_in[10]; const float* br2 = (const float*)d_in[11];
  const float* att2= (const float*)d_in[12]; const float* bias2=(const float*)d_in[13];
  const float* Wres= (const float*)d_in[14]; const float* bres= (const float*)d_in[15];
  const float* Wd  = (const float*)d_in[16]; const float* bd  = (const float*)d_in[17];
  const float* Wg  = (const float*)d_in[18]; const float* bg  = (const float*)d_in[19];
  const float* Wf1 = (const float*)d_in[20]; const float* bf1 = (const float*)d_in[21];
  const float* Wf2 = (const float*)d_in[22]; const float* bf2 = (const float*)d_in[23];
  const float* Wf3 = (const float*)d_in[24]; const float* bf3 = (const float*)d_in[25];
  const int* ei    = (const int*)d_in[26];
  const int* batch = (const int*)d_in[27];
  const int* esrc = ei;
  const int* edst = ei + NE;
  float* outp = (float*)d_out;

  char* p = (char*)d_ws;
  auto carve = [&](size_t bytes) { char* r = p; p += (bytes + 255) & ~(size_t)255; return r; };
  int* bcnt     = (int*)carve((size_t)NBUK * 4);
  int* bbase    = (int*)carve((size_t)(NBUK + 1) * 4);
  int* bcur     = (int*)carve((size_t)NBUK * 4);
  int* tmpv     = (int*)carve((size_t)NE * 4);
  int* ssrc     = (int*)carve((size_t)NE * 4);
  int* offs     = (int*)carve((size_t)(NN + 1) * 4);
  unsigned short* wh = (unsigned short*)carve((size_t)5 * 2 * 8192 * 2);
  unsigned short* wl = (unsigned short*)carve((size_t)5 * 2 * 8192 * 2);
  unsigned short* ximg = (unsigned short*)carve((size_t)NBLK * 8192 * 2);  // fp16 A image (aliased as himg)
  _Float16* xl  = (_Float16*)carve((size_t)NN * FD * 2);
  _Float16* xr  = (_Float16*)carve((size_t)NN * FD * 2);
  _Float16* res = (_Float16*)carve((size_t)NN * FD * 2);
  float* pooled = (float*)carve((size_t)NB * FD * 4);
  unsigned short* himg = ximg;     // ximg dead after layer-1 linears; alias

  hipMemsetAsync(bcnt, 0, (size_t)NBUK * 4, stream);
  hipMemsetAsync(pooled, 0, (size_t)NB * FD * 4, stream);

  dim3 b256(256);
  hipLaunchKernelGGL(k_prep1, dim3(40 + 256), b256, 0, stream,
                     Wl1, Wr1, Wres, Wl2, Wr2, wh, wl, edst, bcnt);
  hipLaunchKernelGGL(k_bscan, dim3(1), b256, 0, stream, bcnt, bbase, bcur);
  hipLaunchKernelGGL(k_prep2, dim3(3125 + 256), b256, 0, stream,
                     x, ximg, esrc, edst, bcur, tmpv);
  hipLaunchKernelGGL(k_csrlin, dim3(NBUK + 3 * NBLK), dim3(512), 0, stream,
                     tmpv, bbase, offs, ssrc, ximg, wh, wl, bl1, br1, bres, xl, xr, res);
  hipLaunchKernelGGL(k_gat1, dim3(NN / 8), b256, 0, stream,
                     xl, xr, offs, ssrc, att1, bias1, res, himg);
  hipLaunchKernelGGL(k_lin2, dim3(NBLK, 2), dim3(512), 0, stream,
                     himg, wh, wl, bl2, br2, xl, xr);
  hipLaunchKernelGGL(k_gatpool, dim3(NN / 8), b256, 0, stream,
                     xl, xr, offs, ssrc, att2, bias2, himg, batch, pooled);
  hipLaunchKernelGGL(k_mlp, dim3(NB), dim3(128), 0, stream, pooled, batch, domain,
                     Wg, bg, Wd, bd, Wf1, bf1, Wf2, bf2, Wf3, bf3, outp);
}